// Round 17
// baseline (108.280 us; speedup 1.0000x reference)
//
#include <hip/hip_runtime.h>

// ---------------- problem constants ----------------
#define HHEADS 16
#define R1 4
#define R2 8
#define HD 64
#define CDIM 1024
#define NSEQ 2048
#define BATCH 2
#define NPROJ 1408            // 64 q1 + 64 k1 + 128 q2 + 128 k2 + 1024 v
#define MROWS (BATCH * NSEQ)  // 4096
#define PCOLS 384             // proj2 keeps only q1/k1/q2/k2 columns
#define SCALE 0.17677669529663687f   // (R1*R2)^-0.5
#define SCALE_LOG2E 0.2550348612f    // SCALE * log2(e): scores in log2 domain

typedef __attribute__((ext_vector_type(8))) short bf16x8;
typedef __attribute__((ext_vector_type(4))) float f32x4;
typedef __attribute__((ext_vector_type(4))) unsigned int u32x4;

// ---------------- bf16 helpers (raw ushort representation) ----------------
__device__ __forceinline__ float bflo(unsigned u) { return __uint_as_float(u << 16); }
__device__ __forceinline__ float bfhi(unsigned u) { return __uint_as_float(u & 0xffff0000u); }
__device__ __forceinline__ unsigned short f2bfr(float f) {
  unsigned u = __float_as_uint(f);
  u += 0x7fffu + ((u >> 16) & 1u);
  return (unsigned short)(u >> 16);
}
__device__ __forceinline__ unsigned pack2(float a, float b) {
  return (unsigned)f2bfr(a) | ((unsigned)f2bfr(b) << 16);
}
// hardware packed f32x2 -> bf16x2 (RNE), single instruction (T12 recipe)
__device__ __forceinline__ unsigned cvtpk(float a, float b) {
  unsigned r;
  asm("v_cvt_pk_bf16_f32 %0, %1, %2" : "=v"(r) : "v"(a), "v"(b));
  return r;
}
// raw v_exp_f32 = 2^x (scores are kept in log2 domain)
__device__ __forceinline__ float exp2fast(float x) {
#if __has_builtin(__builtin_amdgcn_exp2f)
  return __builtin_amdgcn_exp2f(x);
#else
  float r;
  asm("v_exp_f32 %0, %1" : "=v"(r) : "v"(x));
  return r;
#endif
}

// ---------------- fused f32 -> bf16 conversion (WEIGHTS only, R17) --------
// x is converted inline in proj GEMM A-staging. Segments in float4 units:
// Wq1:16384 | Wk1:16384 | Wq2:32768 | Wk2:32768 | Wv:262144 | Wo:262144
__global__ __launch_bounds__(256) void cvt_all_kernel(
    const float* __restrict__ Wq1, const float* __restrict__ Wk1,
    const float* __restrict__ Wq2, const float* __restrict__ Wk2,
    const float* __restrict__ Wv, const float* __restrict__ Wo,
    unsigned short* __restrict__ Wall, unsigned short* __restrict__ Wob) {
  const int total = 622592;
  for (int i = blockIdx.x * blockDim.x + threadIdx.x; i < total;
       i += gridDim.x * blockDim.x) {
    const float* src;
    unsigned short* dst;
    int off;
    if (i < 16384)        { src = Wq1; dst = Wall;          off = i; }
    else if (i < 32768)   { src = Wk1; dst = Wall + 65536;  off = i - 16384; }
    else if (i < 65536)   { src = Wq2; dst = Wall + 131072; off = i - 32768; }
    else if (i < 98304)   { src = Wk2; dst = Wall + 262144; off = i - 65536; }
    else if (i < 360448)  { src = Wv;  dst = Wall + 393216; off = i - 98304; }
    else                  { src = Wo;  dst = Wob;           off = i - 360448; }
    const float4 v = ((const float4*)src)[off];
    ushort4 o;
    o.x = f2bfr(v.x);
    o.y = f2bfr(v.y);
    o.z = f2bfr(v.z);
    o.w = f2bfr(v.w);
    ((ushort4*)dst)[off] = o;
  }
}

// ---------------- async global->LDS (16B per lane) ----------------
__device__ __forceinline__ void gld_lds16(const void* g, void* l) {
  __builtin_amdgcn_global_load_lds(
      (const __attribute__((address_space(1))) void*)g,
      (__attribute__((address_space(3))) void*)l, 16, 0, 0);
}

// ---------------- bf16 GEMM: C[M][N] = A[M][K] * Bw[N][K]^T ----------------
// 64x128 tile, BK=32, double-buffered LDS, one barrier per K-step (R14).
// 1D grid + XCD-chunked decode (R16/T1): each XCD owns 8 consecutive
// y-panels; B + A-panel fit its 4 MB L2.
// R17: OUTMODE 0 stages A from FP32 x in registers (2x float4 load ->
// 4x v_cvt_pk_bf16_f32 -> ds_write_b128; same LDS layout) — deletes the
// separate x conversion pass. OUTMODE 1 keeps gld_lds A-staging (ao bf16).
// OUTMODE 0 epilogue: cols<384 -> proj2 rows; cols>=384 -> transposed vt.
template <int OUTMODE>
__global__ __launch_bounds__(256) void gemm_bt64(
    const float* __restrict__ Af, const unsigned short* __restrict__ A,
    const unsigned short* __restrict__ Bw, unsigned short* __restrict__ Cb,
    unsigned short* __restrict__ vtout, float* __restrict__ Cf,
    const float* __restrict__ bias, int M, int N, int K) {
  __shared__ unsigned short As[2][64 * 32];   // 2 x 4 KB
  __shared__ unsigned short Bs[2][128 * 32];  // 2 x 8 KB
  const int tid = threadIdx.x;
  const int bid = blockIdx.x;
  const int xcd = bid & 7;
  const int ii = bid >> 3;
  const int nx = N >> 7;                 // blocks along N
  const int by = xcd * 8 + ii / nx;      // (M/64)/8 == 8 panels per XCD
  const int bx = ii - (ii / nx) * nx;
  const long brow = (long)by * 64;
  const long bcol = (long)bx * 128;
  const int w = tid >> 6, lane = tid & 63;
  const int lr = lane & 15, kg = lane >> 4;

  f32x4 acc[4][2];
#pragma unroll
  for (int m = 0; m < 4; ++m)
#pragma unroll
    for (int n = 0; n < 2; ++n) acc[m][n] = (f32x4){0.f, 0.f, 0.f, 0.f};

  const int off0 = tid * 16;
  const int row0 = off0 >> 6;
  const int kel0 = (off0 & 63) >> 1;

  const int nk = K >> 5;
  // prologue: stage kt=0 into buffer 0
  {
    if (OUTMODE == 0) {
      const float* ap = Af + (brow + row0) * K + kel0;
      const float4 f0 = *(const float4*)ap;
      const float4 f1 = *(const float4*)(ap + 4);
      u32x4 aw;
      aw[0] = cvtpk(f0.x, f0.y); aw[1] = cvtpk(f0.z, f0.w);
      aw[2] = cvtpk(f1.x, f1.y); aw[3] = cvtpk(f1.z, f1.w);
      *(u32x4*)((char*)As[0] + off0) = aw;
    } else {
      gld_lds16(A + (brow + row0) * K + kel0, (char*)As[0] + off0);
    }
    gld_lds16(Bw + (bcol + row0) * K + kel0, (char*)Bs[0] + off0);
    gld_lds16(Bw + (bcol + 64 + row0) * K + kel0, (char*)Bs[0] + 4096 + off0);
  }
  __syncthreads();

  int buf = 0;
  for (int kt = 0; kt < nk; ++kt) {
    if (kt + 1 < nk) {  // stage next K-step (hides under this step's MFMA)
      const long kbase = (long)(kt + 1) * 32 + kel0;
      if (OUTMODE == 0) {
        const float* ap = Af + (brow + row0) * K + kbase;
        const float4 f0 = *(const float4*)ap;
        const float4 f1 = *(const float4*)(ap + 4);
        u32x4 aw;
        aw[0] = cvtpk(f0.x, f0.y); aw[1] = cvtpk(f0.z, f0.w);
        aw[2] = cvtpk(f1.x, f1.y); aw[3] = cvtpk(f1.z, f1.w);
        *(u32x4*)((char*)As[buf ^ 1] + off0) = aw;
      } else {
        gld_lds16(A + (brow + row0) * K + kbase, (char*)As[buf ^ 1] + off0);
      }
      gld_lds16(Bw + (bcol + row0) * K + kbase, (char*)Bs[buf ^ 1] + off0);
      gld_lds16(Bw + (bcol + 64 + row0) * K + kbase,
                (char*)Bs[buf ^ 1] + 4096 + off0);
    }

    bf16x8 af[4], bfg[2];
#pragma unroll
    for (int m = 0; m < 4; ++m)
      af[m] = *(const bf16x8*)(As[buf] + (m * 16 + lr) * 32 + kg * 8);
#pragma unroll
    for (int n = 0; n < 2; ++n)
      bfg[n] = *(const bf16x8*)(Bs[buf] + (w * 32 + n * 16 + lr) * 32 + kg * 8);
#pragma unroll
    for (int m = 0; m < 4; ++m)
#pragma unroll
      for (int n = 0; n < 2; ++n)
        acc[m][n] = __builtin_amdgcn_mfma_f32_16x16x32_bf16(af[m], bfg[n],
                                                            acc[m][n], 0, 0, 0);
    __syncthreads();  // drains next-step stage loads + protects buffers
    buf ^= 1;
  }

  // epilogue; C/D layout: col = lane&15, row = (lane>>4)*4 + i
  if (OUTMODE == 1) {
#pragma unroll
    for (int m = 0; m < 4; ++m) {
#pragma unroll
      for (int i = 0; i < 4; ++i) {
        const long r = brow + m * 16 + kg * 4 + i;
#pragma unroll
        for (int n = 0; n < 2; ++n) {
          const long c = bcol + w * 32 + n * 16 + lr;
          Cf[r * N + c] = acc[m][n][i] + bias[c];
        }
      }
    }
  } else if (bcol < PCOLS) {  // proj columns -> row-major proj2
#pragma unroll
    for (int m = 0; m < 4; ++m) {
#pragma unroll
      for (int i = 0; i < 4; ++i) {
        const long r = brow + m * 16 + kg * 4 + i;
#pragma unroll
        for (int n = 0; n < 2; ++n) {
          const long c = bcol + w * 32 + n * 16 + lr;
          Cb[r * PCOLS + c] = f2bfr(acc[m][n][i]);
        }
      }
    }
  } else {  // V columns -> transposed write into vt[bh][d][n]
    const int bb = (int)(brow >> 11);        // batch (constant per block)
    const int nn0 = (int)(brow & 2047);
#pragma unroll
    for (int n = 0; n < 2; ++n) {
      const int hd = (int)(bcol + w * 32 + n * 16 + lr) - 384;
      const int h = hd >> 6, d = hd & 63;
      unsigned short* base =
          vtout + ((size_t)((bb * 16 + h) * 64 + d)) * NSEQ + nn0;
#pragma unroll
      for (int m = 0; m < 4; ++m) {
        uint2 u;
        u.x = pack2(acc[m][n][0], acc[m][n][1]);
        u.y = pack2(acc[m][n][2], acc[m][n][3]);
        *(uint2*)(base + m * 16 + kg * 4) = u;
      }
    }
  }
}

// ---------------- kron feature build: qf/kf[bh][n][32] -------------------
// reads proj2 rows (stride PCOLS=384)
__global__ __launch_bounds__(256) void kron_kernel(
    const unsigned short* __restrict__ proj, unsigned short* __restrict__ qf,
    unsigned short* __restrict__ kf) {
  const int bh = blockIdx.x, b = bh >> 4, h = bh & 15;
  const int n = blockIdx.y * 256 + threadIdx.x;
  const unsigned short* row = proj + ((size_t)(b * NSEQ + n)) * PCOLS;
  float q1v[4], k1v[4], q2v[8], k2v[8];
  {
    const uint2 a = *(const uint2*)(row + h * 4);
    q1v[0] = bflo(a.x); q1v[1] = bfhi(a.x); q1v[2] = bflo(a.y); q1v[3] = bfhi(a.y);
    const uint2 c = *(const uint2*)(row + 64 + h * 4);
    k1v[0] = bflo(c.x); k1v[1] = bfhi(c.x); k1v[2] = bflo(c.y); k1v[3] = bfhi(c.y);
    const uint4 d = *(const uint4*)(row + 128 + h * 8);
    q2v[0] = bflo(d.x); q2v[1] = bfhi(d.x); q2v[2] = bflo(d.y); q2v[3] = bfhi(d.y);
    q2v[4] = bflo(d.z); q2v[5] = bfhi(d.z); q2v[6] = bflo(d.w); q2v[7] = bfhi(d.w);
    const uint4 e = *(const uint4*)(row + 256 + h * 8);
    k2v[0] = bflo(e.x); k2v[1] = bfhi(e.x); k2v[2] = bflo(e.y); k2v[3] = bfhi(e.y);
    k2v[4] = bflo(e.z); k2v[5] = bfhi(e.z); k2v[6] = bflo(e.w); k2v[7] = bfhi(e.w);
  }
  unsigned short* oq = qf + ((size_t)bh * NSEQ + n) * 32;
  unsigned short* ok = kf + ((size_t)bh * NSEQ + n) * 32;
#pragma unroll
  for (int i = 0; i < 4; ++i) {
    const float qs = q1v[i] * SCALE_LOG2E;
    uint4 uq, uk;
    uq.x = pack2(qs * q2v[0], qs * q2v[1]);
    uq.y = pack2(qs * q2v[2], qs * q2v[3]);
    uq.z = pack2(qs * q2v[4], qs * q2v[5]);
    uq.w = pack2(qs * q2v[6], qs * q2v[7]);
    uk.x = pack2(k1v[i] * k2v[0], k1v[i] * k2v[1]);
    uk.y = pack2(k1v[i] * k2v[2], k1v[i] * k2v[3]);
    uk.z = pack2(k1v[i] * k2v[4], k1v[i] * k2v[5]);
    uk.w = pack2(k1v[i] * k2v[6], k1v[i] * k2v[7]);
    *(uint4*)(oq + i * 8) = uq;
    *(uint4*)(ok + i * 8) = uk;
  }
}

// ---------------- flash attention (unchanged from R16) --------------------
// KVBLK=64 swizzled LDS double-buffer, balanced 40-item split, m=0
// static-shift softmax, ones-MFMA denominator, s_setprio around compute.
__constant__ int QI_TAB[40] = {3,7,7,10,11,11,11,14,14,15,15,15,15,
                               6,6,9,9,10,10,12,12,13,13,13,13,14,14,
                               2,5,5,8,8,8,9,12,12, 4,4, 1, 0};
__constant__ int C_TAB[40]  = {0,0,1,2,0,1,2,1,3,0,1,2,3,
                               0,1,1,2,0,1,1,3,0,1,2,3,0,2,
                               0,0,1,0,1,2,0,0,2, 0,1, 0, 0};
__constant__ int NCQ[16]   = {1,1,1,1,2,2,2,2,3,3,3,3,4,4,4,4};
__constant__ int EBASE[16] = {0,0,0,0,0,1,2,3,4,6,8,10,12,15,18,21};

__global__ __launch_bounds__(256) void attn_flash(
    const unsigned short* __restrict__ qf, const unsigned short* __restrict__ kf,
    const unsigned short* __restrict__ vt, unsigned short* __restrict__ ao,
    unsigned short* __restrict__ po, unsigned short* __restrict__ po2,
    float* __restrict__ lst) {
  __shared__ __align__(16) char KsB[2 * 4096];  // [2 buf][64 keys][32 feat]
  __shared__ __align__(16) char VsB[2 * 8192];  // [2 buf][64 d][64 keys]

  const int bid = blockIdx.x;
  const int xcd = bid & 7;
  const int idx = bid >> 3;        // [0,160) per XCD
  const int j = idx >> 2;          // item [0,40), heavy-first
  const int g = idx & 3;           // head group
  const int bh = g * 8 + xcd;
  const int qi = QI_TAB[j];
  const int c = C_TAB[j];
  const int nc = NCQ[qi];
  const int T64 = 2 * qi + 2;
  const int tb = (c * T64) / nc;
  const int te = ((c + 1) * T64) / nc;

  const int tid = threadIdx.x;
  const int w = tid >> 6;
  const int lane = tid & 63;
  const int lr = lane & 15, kg = lane >> 4;
  const int b = bh >> 4, h = bh & 15;
  const int qbase = qi * 128 + w * 32;
  const int q0 = qbase + lr;
  const int q1 = qbase + 16 + lr;
  const int qmaxW = qbase + 31;

  const unsigned short* qfh = qf + (size_t)bh * NSEQ * 32;
  const unsigned short* kfh = kf + (size_t)bh * NSEQ * 32;
  const unsigned short* vth = vt + (size_t)bh * 64 * NSEQ;

  const bf16x8 qA = *(const bf16x8*)(qfh + q0 * 32 + kg * 8);
  const bf16x8 qB = *(const bf16x8*)(qfh + q1 * 32 + kg * 8);
  const int krow = (lr >> 2) * 8 + (lr & 3);  // permuted key row for A-frag
  const f32x4 zero = (f32x4){0.f, 0.f, 0.f, 0.f};

  union { u32x4 u; bf16x8 hv; } onesu;
  onesu.u = (u32x4){0x3F803F80u, 0x3F803F80u, 0x3F803F80u, 0x3F803F80u};
  const bf16x8 vones = onesu.hv;  // bf16 1.0 x 8 (A-operand of the l-MFMA)

  const int koffA = krow * 64 + 16 * (kg ^ (lr >> 2));
  const int vx = lr & 7;

  const int ksrow = w * 16 + (lane >> 2);
  const int ksoff = 8 * ((lane & 3) ^ ((ksrow >> 3) & 3));
  const int vd0 = w * 8 + (lane >> 3);
  const int vso0 = 8 * ((lane & 7) ^ (vd0 & 7));
  const int vd1 = vd0 + 32;
  const int vso1 = 8 * ((lane & 7) ^ (vd1 & 7));

  f32x4 oA[4], oB[4], lacA, lacB;
#pragma unroll
  for (int dt = 0; dt < 4; ++dt) { oA[dt] = zero; oB[dt] = zero; }
  lacA = zero; lacB = zero;

  // ---- prologue: stage super-tile tb into buffer 0
  {
    const int k0 = tb * 64;
    gld_lds16(kfh + (size_t)(k0 + ksrow) * 32 + ksoff, KsB + tid * 16);
    gld_lds16(vth + (size_t)vd0 * NSEQ + k0 + vso0, VsB + tid * 16);
    gld_lds16(vth + (size_t)vd1 * NSEQ + k0 + vso1, VsB + 4096 + tid * 16);
  }
  __syncthreads();

  int buf = 0;
  for (int st = tb; st < te; ++st) {
    if (st + 1 < te) {  // stage next super-tile (latency hides under compute)
      const int kn = (st + 1) * 64;
      const int ob = buf ^ 1;
      gld_lds16(kfh + (size_t)(kn + ksrow) * 32 + ksoff,
                KsB + ob * 4096 + tid * 16);
      gld_lds16(vth + (size_t)vd0 * NSEQ + kn + vso0,
                VsB + ob * 8192 + tid * 16);
      gld_lds16(vth + (size_t)vd1 * NSEQ + kn + vso1,
                VsB + ob * 8192 + 4096 + tid * 16);
    }
    const char* Kb = KsB + buf * 4096;
    const char* Vb = VsB + buf * 8192;
#pragma unroll
    for (int sub = 0; sub < 2; ++sub) {
      const int k032 = st * 64 + sub * 32;
      if (k032 <= qmaxW) {  // not fully masked for this wave
        __builtin_amdgcn_s_setprio(1);
        const bf16x8 ck0 = *(const bf16x8*)(Kb + sub * 2048 + koffA);
        const bf16x8 ck1 = *(const bf16x8*)(Kb + sub * 2048 + koffA + 256);

        f32x4 sA0 = __builtin_amdgcn_mfma_f32_16x16x32_bf16(ck0, qA, zero, 0, 0, 0);
        f32x4 sA1 = __builtin_amdgcn_mfma_f32_16x16x32_bf16(ck1, qA, zero, 0, 0, 0);
        f32x4 sB0 = __builtin_amdgcn_mfma_f32_16x16x32_bf16(ck0, qB, zero, 0, 0, 0);
        f32x4 sB1 = __builtin_amdgcn_mfma_f32_16x16x32_bf16(ck1, qB, zero, 0, 0, 0);

        if (k032 + 31 > qbase) {  // diagonal region: causal mask
          const int kb = k032 + kg * 8;
#pragma unroll
          for (int i = 0; i < 4; ++i) {
            if (kb + i > q0) sA0[i] = -1e30f;
            if (kb + 4 + i > q0) sA1[i] = -1e30f;
            if (kb + i > q1) sB0[i] = -1e30f;
            if (kb + 4 + i > q1) sB1[i] = -1e30f;
          }
        }

        // static-shift softmax: p = exp2(s) directly (m = 0)
        const float a0 = exp2fast(sA0[0]), a1 = exp2fast(sA0[1]);
        const float a2 = exp2fast(sA0[2]), a3 = exp2fast(sA0[3]);
        const float a4 = exp2fast(sA1[0]), a5 = exp2fast(sA1[1]);
        const float a6 = exp2fast(sA1[2]), a7 = exp2fast(sA1[3]);
        const float b0 = exp2fast(sB0[0]), b1 = exp2fast(sB0[1]);
        const float b2 = exp2fast(sB0[2]), b3 = exp2fast(sB0[3]);
        const float b4 = exp2fast(sB1[0]), b5 = exp2fast(sB1[1]);
        const float b6 = exp2fast(sB1[2]), b7 = exp2fast(sB1[3]);

        union { u32x4 u; bf16x8 hv; } pA, pB;
        pA.u = (u32x4){cvtpk(a0, a1), cvtpk(a2, a3), cvtpk(a4, a5), cvtpk(a6, a7)};
        pB.u = (u32x4){cvtpk(b0, b1), cvtpk(b2, b3), cvtpk(b4, b5), cvtpk(b6, b7)};

        // softmax denominator on the matrix pipe: l[q] += sum_k p[k][q]
        lacA = __builtin_amdgcn_mfma_f32_16x16x32_bf16(vones, pA.hv, lacA, 0, 0, 0);
        lacB = __builtin_amdgcn_mfma_f32_16x16x32_bf16(vones, pB.hv, lacB, 0, 0, 0);

#pragma unroll
        for (int dt = 0; dt < 4; ++dt) {
          const bf16x8 vfr = *(const bf16x8*)(
              Vb + (dt * 16 + lr) * 128 + ((((sub * 4 + kg) ^ vx) << 4)));
          oA[dt] = __builtin_amdgcn_mfma_f32_16x16x32_bf16(vfr, pA.hv, oA[dt], 0, 0, 0);
          oB[dt] = __builtin_amdgcn_mfma_f32_16x16x32_bf16(vfr, pB.hv, oB[dt], 0, 0, 0);
        }
        __builtin_amdgcn_s_setprio(0);
      }
    }
    __syncthreads();  // drains next-tile stage loads + protects buffers
    buf ^= 1;
  }

  // denominator: every lane's lacA/lacB rows all equal sum_k p[k][q] (A=ones)
  const float ltA = lacA[0];
  const float ltB = lacB[0];

  if (nc == 1) {  // qi 0..3: direct normalized write
    const float invA = 1.f / ltA, invB = 1.f / ltB;
    unsigned short* pAo = ao + ((size_t)(b * NSEQ + q0)) * CDIM + h * 64 + kg * 4;
    unsigned short* pBo = ao + ((size_t)(b * NSEQ + q1)) * CDIM + h * 64 + kg * 4;
#pragma unroll
    for (int dt = 0; dt < 4; ++dt) {
      uint2 ua, ub;
      ua.x = pack2(oA[dt][0] * invA, oA[dt][1] * invA);
      ua.y = pack2(oA[dt][2] * invA, oA[dt][3] * invA);
      ub.x = pack2(oB[dt][0] * invB, oB[dt][1] * invB);
      ub.y = pack2(oB[dt][2] * invB, oB[dt][3] * invB);
      *(uint2*)(pAo + dt * 16) = ua;
      *(uint2*)(pBo + dt * 16) = ub;
    }
  } else {  // unnormalized O: chunk 0 -> ao rows (in place), else -> po slot
    unsigned short *pAo, *pBo;
    if (c == 0) {
      pAo = ao + ((size_t)(b * NSEQ + q0)) * CDIM + h * 64 + kg * 4;
      pBo = ao + ((size_t)(b * NSEQ + q1)) * CDIM + h * 64 + kg * 4;
    } else {
      const int slot = bh * 24 + EBASE[qi] + (c - 1);  // [0,768)
      unsigned short* sp = (slot < 704)
                               ? po + (size_t)slot * 8192
                               : po2 + (size_t)(slot - 704) * 8192;
      pAo = sp + (w * 32 + lr) * 64 + kg * 4;
      pBo = sp + (w * 32 + 16 + lr) * 64 + kg * 4;
    }
#pragma unroll
    for (int dt = 0; dt < 4; ++dt) {
      uint2 ua, ub;
      ua.x = pack2(oA[dt][0], oA[dt][1]);
      ua.y = pack2(oA[dt][2], oA[dt][3]);
      ub.x = pack2(oB[dt][0], oB[dt][1]);
      ub.y = pack2(oB[dt][2], oB[dt][3]);
      *(uint2*)(pAo + dt * 16) = ua;
      *(uint2*)(pBo + dt * 16) = ub;
    }
    if (kg == 0) {
      float* lp = lst + (((size_t)(bh * 16 + qi) * 4 + c) << 7);
      lp[w * 32 + lr] = ltA;
      lp[w * 32 + 16 + lr] = ltB;
    }
  }
}

// ---------------- merge: ao_row = (ao_row + sum(po chunks)) / sum(l) ------
__global__ __launch_bounds__(256) void merge_kernel(
    const unsigned short* __restrict__ po, const unsigned short* __restrict__ po2,
    const float* __restrict__ lst, unsigned short* __restrict__ ao) {
  const int idx = blockIdx.x * 256 + threadIdx.x;  // [0, 393216)
  const int dc = idx & 7;
  const int t = idx >> 3;
  const int r = t & 127;
  const int u = t >> 7;  // [0, 384) = bh*12 + (qi-4)
  const int qi = 4 + (u % 12);
  const int bh = u / 12;
  const int nc = NCQ[qi];
  const int b = bh >> 4, h = bh & 15;

  float L = 0.f;
  const float* lp = lst + (((size_t)(bh * 16 + qi)) << 9);
  for (int c2 = 0; c2 < nc; ++c2) L += lp[(c2 << 7) + r];

  unsigned short* dst =
      ao + ((size_t)(b * NSEQ + qi * 128 + r)) * CDIM + h * 64 + dc * 8;
  const uint4 u0 = *(const uint4*)dst;
  float a0 = bflo(u0.x), a1 = bfhi(u0.x), a2 = bflo(u0.y), a3 = bfhi(u0.y);
  float a4 = bflo(u0.z), a5 = bfhi(u0.z), a6 = bflo(u0.w), a7 = bfhi(u0.w);
  for (int c2 = 1; c2 < nc; ++c2) {
    const int slot = bh * 24 + EBASE[qi] + (c2 - 1);
    const unsigned short* sp = (slot < 704)
                                   ? po + (size_t)slot * 8192
                                   : po2 + (size_t)(slot - 704) * 8192;
    const uint4 up = *(const uint4*)(sp + r * 64 + dc * 8);
    a0 += bflo(up.x); a1 += bfhi(up.x); a2 += bflo(up.y); a3 += bfhi(up.y);
    a4 += bflo(up.z); a5 += bfhi(up.z); a6 += bflo(up.w); a7 += bfhi(up.w);
  }
  const float inv = 1.f / L;
  uint4 o;
  o.x = pack2(a0 * inv, a1 * inv);
  o.y = pack2(a2 * inv, a3 * inv);
  o.z = pack2(a4 * inv, a5 * inv);
  o.w = pack2(a6 * inv, a7 * inv);
  *(uint4*)dst = o;
}

// ---------------- launch ----------------
extern "C" void kernel_launch(void* const* d_in, const int* in_sizes, int n_in,
                              void* d_out, int out_size, void* d_ws,
                              size_t ws_size, hipStream_t stream) {
  (void)in_sizes; (void)n_in; (void)out_size; (void)ws_size;
  const float* x   = (const float*)d_in[0];
  const float* Wq1 = (const float*)d_in[1];
  const float* Wk1 = (const float*)d_in[2];
  const float* Wq2 = (const float*)d_in[3];
  const float* Wk2 = (const float*)d_in[4];
  const float* Wv  = (const float*)d_in[5];
  const float* Wo  = (const float*)d_in[6];
  const float* bo  = (const float*)d_in[7];
  float* out = (float*)d_out;

  char* ws = (char*)d_ws;
  unsigned short* ao   = (unsigned short*)(ws);              // 8 MB attn out
  unsigned short* Wall = (unsigned short*)(ws + 8388608);    // 2,883,584 B
  unsigned short* Wob  = (unsigned short*)(ws + 11272192);   // 2 MB
  unsigned short* proj = (unsigned short*)(ws + 13369344);   // proj2: 3 MB used
  unsigned short* qf   = (unsigned short*)(ws + 24903680);   // 4 MB
  unsigned short* kf   = (unsigned short*)(ws + 29097984);   // 4 MB
  unsigned short* vt   = (unsigned short*)(ws + 33292288);   // 8 MB
  // split-K partial slots (16KB each): 704 overlay proj region (dead after
  // kron), 64 overlay Wall (dead after proj GEMM); l-stats after po2.
  unsigned short* po   = proj;
  unsigned short* po2  = Wall;
  float*          lst  = (float*)(ws + 8388608 + 1048576);   // 1 MB

  cvt_all_kernel<<<dim3(1024), dim3(256), 0, stream>>>(
      Wq1, Wk1, Wq2, Wk2, Wv, Wo, Wall, Wob);

  // proj GEMM: A staged from f32 x inline; cols<384 -> proj2; cols>=384 -> vt
  gemm_bt64<0><<<dim3((NPROJ / 128) * (MROWS / 64)), dim3(256), 0, stream>>>(
      x, (const unsigned short*)nullptr, Wall, proj, vt, (float*)nullptr,
      (const float*)nullptr, MROWS, NPROJ, CDIM);

  kron_kernel<<<dim3(BATCH * HHEADS, NSEQ / 256), dim3(256), 0, stream>>>(proj, qf, kf);

  attn_flash<<<dim3(1280), dim3(256), 0, stream>>>(qf, kf, vt, ao, po, po2, lst);
  merge_kernel<<<dim3(1536), dim3(256), 0, stream>>>(po, po2, lst, ao);

  gemm_bt64<1><<<dim3((CDIM / 128) * (MROWS / 64)), dim3(256), 0, stream>>>(
      (const float*)nullptr, ao, Wob, (unsigned short*)nullptr,
      (unsigned short*)nullptr, out, bo, MROWS, CDIM, CDIM);
}

// Round 18
// 100.838 us; speedup vs baseline: 1.0738x; 1.0738x over previous
//
#include <hip/hip_runtime.h>

// ---------------- problem constants ----------------
#define HHEADS 16
#define R1 4
#define R2 8
#define HD 64
#define CDIM 1024
#define NSEQ 2048
#define BATCH 2
#define NPROJ 1408            // 64 q1 + 64 k1 + 128 q2 + 128 k2 + 1024 v
#define MROWS (BATCH * NSEQ)  // 4096
#define PCOLS 384             // proj2 keeps only q1/k1/q2/k2 columns
#define SCALE 0.17677669529663687f   // (R1*R2)^-0.5
#define SCALE_LOG2E 0.2550348612f    // SCALE * log2(e): scores in log2 domain

typedef __attribute__((ext_vector_type(8))) short bf16x8;
typedef __attribute__((ext_vector_type(4))) float f32x4;
typedef __attribute__((ext_vector_type(4))) unsigned int u32x4;

// ---------------- bf16 helpers (raw ushort representation) ----------------
__device__ __forceinline__ float bflo(unsigned u) { return __uint_as_float(u << 16); }
__device__ __forceinline__ float bfhi(unsigned u) { return __uint_as_float(u & 0xffff0000u); }
__device__ __forceinline__ unsigned short f2bfr(float f) {
  unsigned u = __float_as_uint(f);
  u += 0x7fffu + ((u >> 16) & 1u);
  return (unsigned short)(u >> 16);
}
__device__ __forceinline__ unsigned pack2(float a, float b) {
  return (unsigned)f2bfr(a) | ((unsigned)f2bfr(b) << 16);
}
// hardware packed f32x2 -> bf16x2 (RNE), single instruction (T12 recipe)
__device__ __forceinline__ unsigned cvtpk(float a, float b) {
  unsigned r;
  asm("v_cvt_pk_bf16_f32 %0, %1, %2" : "=v"(r) : "v"(a), "v"(b));
  return r;
}
// raw v_exp_f32 = 2^x (scores are kept in log2 domain)
__device__ __forceinline__ float exp2fast(float x) {
#if __has_builtin(__builtin_amdgcn_exp2f)
  return __builtin_amdgcn_exp2f(x);
#else
  float r;
  asm("v_exp_f32 %0, %1" : "=v"(r) : "v"(x));
  return r;
#endif
}

// ---------------- fused f32 -> bf16 conversion (all 7 inputs, 1 launch) ---
__global__ __launch_bounds__(256) void cvt_all_kernel(
    const float* __restrict__ x, const float* __restrict__ Wq1,
    const float* __restrict__ Wk1, const float* __restrict__ Wq2,
    const float* __restrict__ Wk2, const float* __restrict__ Wv,
    const float* __restrict__ Wo, unsigned short* __restrict__ xb,
    unsigned short* __restrict__ Wall, unsigned short* __restrict__ Wob) {
  const int total = 1671168;
  for (int i = blockIdx.x * blockDim.x + threadIdx.x; i < total;
       i += gridDim.x * blockDim.x) {
    const float* src;
    unsigned short* dst;
    int off;
    if (i < 1048576)      { src = x;   dst = xb;            off = i; }
    else if (i < 1064960) { src = Wq1; dst = Wall;          off = i - 1048576; }
    else if (i < 1081344) { src = Wk1; dst = Wall + 65536;  off = i - 1064960; }
    else if (i < 1114112) { src = Wq2; dst = Wall + 131072; off = i - 1081344; }
    else if (i < 1146880) { src = Wk2; dst = Wall + 262144; off = i - 1114112; }
    else if (i < 1409024) { src = Wv;  dst = Wall + 393216; off = i - 1146880; }
    else                  { src = Wo;  dst = Wob;           off = i - 1409024; }
    const float4 v = ((const float4*)src)[off];
    ushort4 o;
    o.x = f2bfr(v.x);
    o.y = f2bfr(v.y);
    o.z = f2bfr(v.z);
    o.w = f2bfr(v.w);
    ((ushort4*)dst)[off] = o;
  }
}

// ---------------- async global->LDS (16B per lane) ----------------
__device__ __forceinline__ void gld_lds16(const void* g, void* l) {
  __builtin_amdgcn_global_load_lds(
      (const __attribute__((address_space(1))) void*)g,
      (__attribute__((address_space(3))) void*)l, 16, 0, 0);
}

// ---------------- bf16 GEMM: C[M][N] = A[M][K] * Bw[N][K]^T ----------------
// 64x128 tile, BK=32, double-buffered LDS, one barrier per K-step (R14).
// 1D grid + XCD-chunked decode (R16/T1): each XCD owns 8 consecutive
// y-panels; B + A-panel fit its 4 MB L2.
// R18: both-sides LDS XOR swizzle (T2/m173; fixes the measured 2.16M
// SQ_LDS_BANK_CONFLICT = 8-way on 64B-row column reads):
//   16B chunk' = chunk ^ ((row>>1)&3). Staging keeps linear gld_lds dests
//   and pre-swizzles the GLOBAL source chunk ((tid&3)^((tid>>3)&3));
//   reads use kgx = (kg^((lr>>1)&3))*8 — (row-parity, chunk') pairs cover
//   8 banks x 2 lanes = conflict-free floor.
// OUTMODE 0 (proj): cols<384 -> proj2 rows; cols>=384 -> transposed vt.
// OUTMODE 1 (out): f32 + bias.
template <int OUTMODE>
__global__ __launch_bounds__(256) void gemm_bt64(
    const unsigned short* __restrict__ A, const unsigned short* __restrict__ Bw,
    unsigned short* __restrict__ Cb, unsigned short* __restrict__ vtout,
    float* __restrict__ Cf, const float* __restrict__ bias, int M, int N,
    int K) {
  __shared__ unsigned short As[2][64 * 32];   // 2 x 4 KB
  __shared__ unsigned short Bs[2][128 * 32];  // 2 x 8 KB
  const int tid = threadIdx.x;
  const int bid = blockIdx.x;
  const int xcd = bid & 7;
  const int ii = bid >> 3;
  const int nx = N >> 7;                 // blocks along N
  const int by = xcd * 8 + ii / nx;      // (M/64)/8 == 8 panels per XCD
  const int bx = ii - (ii / nx) * nx;
  const long brow = (long)by * 64;
  const long bcol = (long)bx * 128;
  const int w = tid >> 6, lane = tid & 63;
  const int lr = lane & 15, kg = lane >> 4;

  f32x4 acc[4][2];
#pragma unroll
  for (int m = 0; m < 4; ++m)
#pragma unroll
    for (int n = 0; n < 2; ++n) acc[m][n] = (f32x4){0.f, 0.f, 0.f, 0.f};

  const int off0 = tid * 16;
  const int row0 = off0 >> 6;
  // pre-swizzled global source chunk (involution with the read XOR)
  const int kel0 = (((tid & 3) ^ ((tid >> 3) & 3)) << 3);
  // swizzled read chunk offset (elements); lane-constant for all m/n rows
  const int kgx = ((kg ^ ((lr >> 1) & 3)) << 3);

  const int nk = K >> 5;
  // prologue: stage kt=0 into buffer 0
  {
    gld_lds16(A + (brow + row0) * K + kel0, (char*)As[0] + off0);
    gld_lds16(Bw + (bcol + row0) * K + kel0, (char*)Bs[0] + off0);
    gld_lds16(Bw + (bcol + 64 + row0) * K + kel0, (char*)Bs[0] + 4096 + off0);
  }
  __syncthreads();

  int buf = 0;
  for (int kt = 0; kt < nk; ++kt) {
    if (kt + 1 < nk) {  // stage next K-step (hides under this step's MFMA)
      const long kbase = (long)(kt + 1) * 32 + kel0;
      gld_lds16(A + (brow + row0) * K + kbase, (char*)As[buf ^ 1] + off0);
      gld_lds16(Bw + (bcol + row0) * K + kbase, (char*)Bs[buf ^ 1] + off0);
      gld_lds16(Bw + (bcol + 64 + row0) * K + kbase,
                (char*)Bs[buf ^ 1] + 4096 + off0);
    }

    bf16x8 af[4], bfg[2];
#pragma unroll
    for (int m = 0; m < 4; ++m)
      af[m] = *(const bf16x8*)(As[buf] + (m * 16 + lr) * 32 + kgx);
#pragma unroll
    for (int n = 0; n < 2; ++n)
      bfg[n] = *(const bf16x8*)(Bs[buf] + (w * 32 + n * 16 + lr) * 32 + kgx);
#pragma unroll
    for (int m = 0; m < 4; ++m)
#pragma unroll
      for (int n = 0; n < 2; ++n)
        acc[m][n] = __builtin_amdgcn_mfma_f32_16x16x32_bf16(af[m], bfg[n],
                                                            acc[m][n], 0, 0, 0);
    __syncthreads();  // drains next-step stage loads + protects buffers
    buf ^= 1;
  }

  // epilogue; C/D layout: col = lane&15, row = (lane>>4)*4 + i
  if (OUTMODE == 1) {
#pragma unroll
    for (int m = 0; m < 4; ++m) {
#pragma unroll
      for (int i = 0; i < 4; ++i) {
        const long r = brow + m * 16 + kg * 4 + i;
#pragma unroll
        for (int n = 0; n < 2; ++n) {
          const long c = bcol + w * 32 + n * 16 + lr;
          Cf[r * N + c] = acc[m][n][i] + bias[c];
        }
      }
    }
  } else if (bcol < PCOLS) {  // proj columns -> row-major proj2
#pragma unroll
    for (int m = 0; m < 4; ++m) {
#pragma unroll
      for (int i = 0; i < 4; ++i) {
        const long r = brow + m * 16 + kg * 4 + i;
#pragma unroll
        for (int n = 0; n < 2; ++n) {
          const long c = bcol + w * 32 + n * 16 + lr;
          Cb[r * PCOLS + c] = f2bfr(acc[m][n][i]);
        }
      }
    }
  } else {  // V columns -> transposed write into vt[bh][d][n]
    const int bb = (int)(brow >> 11);        // batch (constant per block)
    const int nn0 = (int)(brow & 2047);
#pragma unroll
    for (int n = 0; n < 2; ++n) {
      const int hd = (int)(bcol + w * 32 + n * 16 + lr) - 384;
      const int h = hd >> 6, d = hd & 63;
      unsigned short* base =
          vtout + ((size_t)((bb * 16 + h) * 64 + d)) * NSEQ + nn0;
#pragma unroll
      for (int m = 0; m < 4; ++m) {
        uint2 u;
        u.x = pack2(acc[m][n][0], acc[m][n][1]);
        u.y = pack2(acc[m][n][2], acc[m][n][3]);
        *(uint2*)(base + m * 16 + kg * 4) = u;
      }
    }
  }
}

// ---------------- kron feature build: qf/kf[bh][n][32] -------------------
// reads proj2 rows (stride PCOLS=384)
__global__ __launch_bounds__(256) void kron_kernel(
    const unsigned short* __restrict__ proj, unsigned short* __restrict__ qf,
    unsigned short* __restrict__ kf) {
  const int bh = blockIdx.x, b = bh >> 4, h = bh & 15;
  const int n = blockIdx.y * 256 + threadIdx.x;
  const unsigned short* row = proj + ((size_t)(b * NSEQ + n)) * PCOLS;
  float q1v[4], k1v[4], q2v[8], k2v[8];
  {
    const uint2 a = *(const uint2*)(row + h * 4);
    q1v[0] = bflo(a.x); q1v[1] = bfhi(a.x); q1v[2] = bflo(a.y); q1v[3] = bfhi(a.y);
    const uint2 c = *(const uint2*)(row + 64 + h * 4);
    k1v[0] = bflo(c.x); k1v[1] = bfhi(c.x); k1v[2] = bflo(c.y); k1v[3] = bfhi(c.y);
    const uint4 d = *(const uint4*)(row + 128 + h * 8);
    q2v[0] = bflo(d.x); q2v[1] = bfhi(d.x); q2v[2] = bflo(d.y); q2v[3] = bfhi(d.y);
    q2v[4] = bflo(d.z); q2v[5] = bfhi(d.z); q2v[6] = bflo(d.w); q2v[7] = bfhi(d.w);
    const uint4 e = *(const uint4*)(row + 256 + h * 8);
    k2v[0] = bflo(e.x); k2v[1] = bfhi(e.x); k2v[2] = bflo(e.y); k2v[3] = bfhi(e.y);
    k2v[4] = bflo(e.z); k2v[5] = bfhi(e.z); k2v[6] = bflo(e.w); k2v[7] = bfhi(e.w);
  }
  unsigned short* oq = qf + ((size_t)bh * NSEQ + n) * 32;
  unsigned short* ok = kf + ((size_t)bh * NSEQ + n) * 32;
#pragma unroll
  for (int i = 0; i < 4; ++i) {
    const float qs = q1v[i] * SCALE_LOG2E;
    uint4 uq, uk;
    uq.x = pack2(qs * q2v[0], qs * q2v[1]);
    uq.y = pack2(qs * q2v[2], qs * q2v[3]);
    uq.z = pack2(qs * q2v[4], qs * q2v[5]);
    uq.w = pack2(qs * q2v[6], qs * q2v[7]);
    uk.x = pack2(k1v[i] * k2v[0], k1v[i] * k2v[1]);
    uk.y = pack2(k1v[i] * k2v[2], k1v[i] * k2v[3]);
    uk.z = pack2(k1v[i] * k2v[4], k1v[i] * k2v[5]);
    uk.w = pack2(k1v[i] * k2v[6], k1v[i] * k2v[7]);
    *(uint4*)(oq + i * 8) = uq;
    *(uint4*)(ok + i * 8) = uk;
  }
}

// ---------------- flash attention (unchanged from R16) --------------------
// KVBLK=64 swizzled LDS double-buffer, balanced 40-item split, m=0
// static-shift softmax, ones-MFMA denominator, s_setprio around compute.
__constant__ int QI_TAB[40] = {3,7,7,10,11,11,11,14,14,15,15,15,15,
                               6,6,9,9,10,10,12,12,13,13,13,13,14,14,
                               2,5,5,8,8,8,9,12,12, 4,4, 1, 0};
__constant__ int C_TAB[40]  = {0,0,1,2,0,1,2,1,3,0,1,2,3,
                               0,1,1,2,0,1,1,3,0,1,2,3,0,2,
                               0,0,1,0,1,2,0,0,2, 0,1, 0, 0};
__constant__ int NCQ[16]   = {1,1,1,1,2,2,2,2,3,3,3,3,4,4,4,4};
__constant__ int EBASE[16] = {0,0,0,0,0,1,2,3,4,6,8,10,12,15,18,21};

__global__ __launch_bounds__(256) void attn_flash(
    const unsigned short* __restrict__ qf, const unsigned short* __restrict__ kf,
    const unsigned short* __restrict__ vt, unsigned short* __restrict__ ao,
    unsigned short* __restrict__ po, unsigned short* __restrict__ po2,
    float* __restrict__ lst) {
  __shared__ __align__(16) char KsB[2 * 4096];  // [2 buf][64 keys][32 feat]
  __shared__ __align__(16) char VsB[2 * 8192];  // [2 buf][64 d][64 keys]

  const int bid = blockIdx.x;
  const int xcd = bid & 7;
  const int idx = bid >> 3;        // [0,160) per XCD
  const int j = idx >> 2;          // item [0,40), heavy-first
  const int g = idx & 3;           // head group
  const int bh = g * 8 + xcd;
  const int qi = QI_TAB[j];
  const int c = C_TAB[j];
  const int nc = NCQ[qi];
  const int T64 = 2 * qi + 2;
  const int tb = (c * T64) / nc;
  const int te = ((c + 1) * T64) / nc;

  const int tid = threadIdx.x;
  const int w = tid >> 6;
  const int lane = tid & 63;
  const int lr = lane & 15, kg = lane >> 4;
  const int b = bh >> 4, h = bh & 15;
  const int qbase = qi * 128 + w * 32;
  const int q0 = qbase + lr;
  const int q1 = qbase + 16 + lr;
  const int qmaxW = qbase + 31;

  const unsigned short* qfh = qf + (size_t)bh * NSEQ * 32;
  const unsigned short* kfh = kf + (size_t)bh * NSEQ * 32;
  const unsigned short* vth = vt + (size_t)bh * 64 * NSEQ;

  const bf16x8 qA = *(const bf16x8*)(qfh + q0 * 32 + kg * 8);
  const bf16x8 qB = *(const bf16x8*)(qfh + q1 * 32 + kg * 8);
  const int krow = (lr >> 2) * 8 + (lr & 3);  // permuted key row for A-frag
  const f32x4 zero = (f32x4){0.f, 0.f, 0.f, 0.f};

  union { u32x4 u; bf16x8 hv; } onesu;
  onesu.u = (u32x4){0x3F803F80u, 0x3F803F80u, 0x3F803F80u, 0x3F803F80u};
  const bf16x8 vones = onesu.hv;  // bf16 1.0 x 8 (A-operand of the l-MFMA)

  const int koffA = krow * 64 + 16 * (kg ^ (lr >> 2));
  const int vx = lr & 7;

  const int ksrow = w * 16 + (lane >> 2);
  const int ksoff = 8 * ((lane & 3) ^ ((ksrow >> 3) & 3));
  const int vd0 = w * 8 + (lane >> 3);
  const int vso0 = 8 * ((lane & 7) ^ (vd0 & 7));
  const int vd1 = vd0 + 32;
  const int vso1 = 8 * ((lane & 7) ^ (vd1 & 7));

  f32x4 oA[4], oB[4], lacA, lacB;
#pragma unroll
  for (int dt = 0; dt < 4; ++dt) { oA[dt] = zero; oB[dt] = zero; }
  lacA = zero; lacB = zero;

  // ---- prologue: stage super-tile tb into buffer 0
  {
    const int k0 = tb * 64;
    gld_lds16(kfh + (size_t)(k0 + ksrow) * 32 + ksoff, KsB + tid * 16);
    gld_lds16(vth + (size_t)vd0 * NSEQ + k0 + vso0, VsB + tid * 16);
    gld_lds16(vth + (size_t)vd1 * NSEQ + k0 + vso1, VsB + 4096 + tid * 16);
  }
  __syncthreads();

  int buf = 0;
  for (int st = tb; st < te; ++st) {
    if (st + 1 < te) {  // stage next super-tile (latency hides under compute)
      const int kn = (st + 1) * 64;
      const int ob = buf ^ 1;
      gld_lds16(kfh + (size_t)(kn + ksrow) * 32 + ksoff,
                KsB + ob * 4096 + tid * 16);
      gld_lds16(vth + (size_t)vd0 * NSEQ + kn + vso0,
                VsB + ob * 8192 + tid * 16);
      gld_lds16(vth + (size_t)vd1 * NSEQ + kn + vso1,
                VsB + ob * 8192 + 4096 + tid * 16);
    }
    const char* Kb = KsB + buf * 4096;
    const char* Vb = VsB + buf * 8192;
#pragma unroll
    for (int sub = 0; sub < 2; ++sub) {
      const int k032 = st * 64 + sub * 32;
      if (k032 <= qmaxW) {  // not fully masked for this wave
        __builtin_amdgcn_s_setprio(1);
        const bf16x8 ck0 = *(const bf16x8*)(Kb + sub * 2048 + koffA);
        const bf16x8 ck1 = *(const bf16x8*)(Kb + sub * 2048 + koffA + 256);

        f32x4 sA0 = __builtin_amdgcn_mfma_f32_16x16x32_bf16(ck0, qA, zero, 0, 0, 0);
        f32x4 sA1 = __builtin_amdgcn_mfma_f32_16x16x32_bf16(ck1, qA, zero, 0, 0, 0);
        f32x4 sB0 = __builtin_amdgcn_mfma_f32_16x16x32_bf16(ck0, qB, zero, 0, 0, 0);
        f32x4 sB1 = __builtin_amdgcn_mfma_f32_16x16x32_bf16(ck1, qB, zero, 0, 0, 0);

        if (k032 + 31 > qbase) {  // diagonal region: causal mask
          const int kb = k032 + kg * 8;
#pragma unroll
          for (int i = 0; i < 4; ++i) {
            if (kb + i > q0) sA0[i] = -1e30f;
            if (kb + 4 + i > q0) sA1[i] = -1e30f;
            if (kb + i > q1) sB0[i] = -1e30f;
            if (kb + 4 + i > q1) sB1[i] = -1e30f;
          }
        }

        // static-shift softmax: p = exp2(s) directly (m = 0)
        const float a0 = exp2fast(sA0[0]), a1 = exp2fast(sA0[1]);
        const float a2 = exp2fast(sA0[2]), a3 = exp2fast(sA0[3]);
        const float a4 = exp2fast(sA1[0]), a5 = exp2fast(sA1[1]);
        const float a6 = exp2fast(sA1[2]), a7 = exp2fast(sA1[3]);
        const float b0 = exp2fast(sB0[0]), b1 = exp2fast(sB0[1]);
        const float b2 = exp2fast(sB0[2]), b3 = exp2fast(sB0[3]);
        const float b4 = exp2fast(sB1[0]), b5 = exp2fast(sB1[1]);
        const float b6 = exp2fast(sB1[2]), b7 = exp2fast(sB1[3]);

        union { u32x4 u; bf16x8 hv; } pA, pB;
        pA.u = (u32x4){cvtpk(a0, a1), cvtpk(a2, a3), cvtpk(a4, a5), cvtpk(a6, a7)};
        pB.u = (u32x4){cvtpk(b0, b1), cvtpk(b2, b3), cvtpk(b4, b5), cvtpk(b6, b7)};

        // softmax denominator on the matrix pipe: l[q] += sum_k p[k][q]
        lacA = __builtin_amdgcn_mfma_f32_16x16x32_bf16(vones, pA.hv, lacA, 0, 0, 0);
        lacB = __builtin_amdgcn_mfma_f32_16x16x32_bf16(vones, pB.hv, lacB, 0, 0, 0);

#pragma unroll
        for (int dt = 0; dt < 4; ++dt) {
          const bf16x8 vfr = *(const bf16x8*)(
              Vb + (dt * 16 + lr) * 128 + ((((sub * 4 + kg) ^ vx) << 4)));
          oA[dt] = __builtin_amdgcn_mfma_f32_16x16x32_bf16(vfr, pA.hv, oA[dt], 0, 0, 0);
          oB[dt] = __builtin_amdgcn_mfma_f32_16x16x32_bf16(vfr, pB.hv, oB[dt], 0, 0, 0);
        }
        __builtin_amdgcn_s_setprio(0);
      }
    }
    __syncthreads();  // drains next-tile stage loads + protects buffers
    buf ^= 1;
  }

  // denominator: every lane's lacA/lacB rows all equal sum_k p[k][q] (A=ones)
  const float ltA = lacA[0];
  const float ltB = lacB[0];

  if (nc == 1) {  // qi 0..3: direct normalized write
    const float invA = 1.f / ltA, invB = 1.f / ltB;
    unsigned short* pAo = ao + ((size_t)(b * NSEQ + q0)) * CDIM + h * 64 + kg * 4;
    unsigned short* pBo = ao + ((size_t)(b * NSEQ + q1)) * CDIM + h * 64 + kg * 4;
#pragma unroll
    for (int dt = 0; dt < 4; ++dt) {
      uint2 ua, ub;
      ua.x = pack2(oA[dt][0] * invA, oA[dt][1] * invA);
      ua.y = pack2(oA[dt][2] * invA, oA[dt][3] * invA);
      ub.x = pack2(oB[dt][0] * invB, oB[dt][1] * invB);
      ub.y = pack2(oB[dt][2] * invB, oB[dt][3] * invB);
      *(uint2*)(pAo + dt * 16) = ua;
      *(uint2*)(pBo + dt * 16) = ub;
    }
  } else {  // unnormalized O: chunk 0 -> ao rows (in place), else -> po slot
    unsigned short *pAo, *pBo;
    if (c == 0) {
      pAo = ao + ((size_t)(b * NSEQ + q0)) * CDIM + h * 64 + kg * 4;
      pBo = ao + ((size_t)(b * NSEQ + q1)) * CDIM + h * 64 + kg * 4;
    } else {
      const int slot = bh * 24 + EBASE[qi] + (c - 1);  // [0,768)
      unsigned short* sp = (slot < 704)
                               ? po + (size_t)slot * 8192
                               : po2 + (size_t)(slot - 704) * 8192;
      pAo = sp + (w * 32 + lr) * 64 + kg * 4;
      pBo = sp + (w * 32 + 16 + lr) * 64 + kg * 4;
    }
#pragma unroll
    for (int dt = 0; dt < 4; ++dt) {
      uint2 ua, ub;
      ua.x = pack2(oA[dt][0], oA[dt][1]);
      ua.y = pack2(oA[dt][2], oA[dt][3]);
      ub.x = pack2(oB[dt][0], oB[dt][1]);
      ub.y = pack2(oB[dt][2], oB[dt][3]);
      *(uint2*)(pAo + dt * 16) = ua;
      *(uint2*)(pBo + dt * 16) = ub;
    }
    if (kg == 0) {
      float* lp = lst + (((size_t)(bh * 16 + qi) * 4 + c) << 7);
      lp[w * 32 + lr] = ltA;
      lp[w * 32 + 16 + lr] = ltB;
    }
  }
}

// ---------------- merge: ao_row = (ao_row + sum(po chunks)) / sum(l) ------
__global__ __launch_bounds__(256) void merge_kernel(
    const unsigned short* __restrict__ po, const unsigned short* __restrict__ po2,
    const float* __restrict__ lst, unsigned short* __restrict__ ao) {
  const int idx = blockIdx.x * 256 + threadIdx.x;  // [0, 393216)
  const int dc = idx & 7;
  const int t = idx >> 3;
  const int r = t & 127;
  const int u = t >> 7;  // [0, 384) = bh*12 + (qi-4)
  const int qi = 4 + (u % 12);
  const int bh = u / 12;
  const int nc = NCQ[qi];
  const int b = bh >> 4, h = bh & 15;

  float L = 0.f;
  const float* lp = lst + (((size_t)(bh * 16 + qi)) << 9);
  for (int c2 = 0; c2 < nc; ++c2) L += lp[(c2 << 7) + r];

  unsigned short* dst =
      ao + ((size_t)(b * NSEQ + qi * 128 + r)) * CDIM + h * 64 + dc * 8;
  const uint4 u0 = *(const uint4*)dst;
  float a0 = bflo(u0.x), a1 = bfhi(u0.x), a2 = bflo(u0.y), a3 = bfhi(u0.y);
  float a4 = bflo(u0.z), a5 = bfhi(u0.z), a6 = bflo(u0.w), a7 = bfhi(u0.w);
  for (int c2 = 1; c2 < nc; ++c2) {
    const int slot = bh * 24 + EBASE[qi] + (c2 - 1);
    const unsigned short* sp = (slot < 704)
                                   ? po + (size_t)slot * 8192
                                   : po2 + (size_t)(slot - 704) * 8192;
    const uint4 up = *(const uint4*)(sp + r * 64 + dc * 8);
    a0 += bflo(up.x); a1 += bfhi(up.x); a2 += bflo(up.y); a3 += bfhi(up.y);
    a4 += bflo(up.z); a5 += bfhi(up.z); a6 += bflo(up.w); a7 += bfhi(up.w);
  }
  const float inv = 1.f / L;
  uint4 o;
  o.x = pack2(a0 * inv, a1 * inv);
  o.y = pack2(a2 * inv, a3 * inv);
  o.z = pack2(a4 * inv, a5 * inv);
  o.w = pack2(a6 * inv, a7 * inv);
  *(uint4*)dst = o;
}

// ---------------- launch ----------------
extern "C" void kernel_launch(void* const* d_in, const int* in_sizes, int n_in,
                              void* d_out, int out_size, void* d_ws,
                              size_t ws_size, hipStream_t stream) {
  (void)in_sizes; (void)n_in; (void)out_size; (void)ws_size;
  const float* x   = (const float*)d_in[0];
  const float* Wq1 = (const float*)d_in[1];
  const float* Wk1 = (const float*)d_in[2];
  const float* Wq2 = (const float*)d_in[3];
  const float* Wk2 = (const float*)d_in[4];
  const float* Wv  = (const float*)d_in[5];
  const float* Wo  = (const float*)d_in[6];
  const float* bo  = (const float*)d_in[7];
  float* out = (float*)d_out;

  char* ws = (char*)d_ws;
  unsigned short* xb   = (unsigned short*)(ws);              // 8 MB (reused as ao)
  unsigned short* Wall = (unsigned short*)(ws + 8388608);    // 2,883,584 B
  unsigned short* Wob  = (unsigned short*)(ws + 11272192);   // 2 MB
  unsigned short* proj = (unsigned short*)(ws + 13369344);   // proj2: 3 MB used
  unsigned short* qf   = (unsigned short*)(ws + 24903680);   // 4 MB
  unsigned short* kf   = (unsigned short*)(ws + 29097984);   // 4 MB
  unsigned short* vt   = (unsigned short*)(ws + 33292288);   // 8 MB
  unsigned short* ao   = xb;  // xb dead after proj GEMM
  // split-K partial slots (16KB each): 704 overlay proj region (dead after
  // kron), 64 overlay Wall (dead after proj GEMM); l-stats after po2.
  unsigned short* po   = proj;
  unsigned short* po2  = Wall;
  float*          lst  = (float*)(ws + 8388608 + 1048576);   // 1 MB

  cvt_all_kernel<<<dim3(2048), dim3(256), 0, stream>>>(
      x, Wq1, Wk1, Wq2, Wk2, Wv, Wo, xb, Wall, Wob);

  // proj GEMM: cols<384 -> proj2 rows; cols>=384 -> transposed V into vt
  gemm_bt64<0><<<dim3((NPROJ / 128) * (MROWS / 64)), dim3(256), 0, stream>>>(
      xb, Wall, proj, vt, (float*)nullptr, (const float*)nullptr, MROWS,
      NPROJ, CDIM);

  kron_kernel<<<dim3(BATCH * HHEADS, NSEQ / 256), dim3(256), 0, stream>>>(proj, qf, kf);

  attn_flash<<<dim3(1280), dim3(256), 0, stream>>>(qf, kf, vt, ao, po, po2, lst);
  merge_kernel<<<dim3(1536), dim3(256), 0, stream>>>(po, po2, lst, ao);

  gemm_bt64<1><<<dim3((CDIM / 128) * (MROWS / 64)), dim3(256), 0, stream>>>(
      ao, Wob, (unsigned short*)nullptr, (unsigned short*)nullptr, out, bo,
      MROWS, CDIM, CDIM);
}

// Round 19
// 93.388 us; speedup vs baseline: 1.1595x; 1.0798x over previous
//
#include <hip/hip_runtime.h>

// ---------------- problem constants ----------------
#define HHEADS 16
#define R1 4
#define R2 8
#define HD 64
#define CDIM 1024
#define NSEQ 2048
#define BATCH 2
#define NPROJ 1408            // 64 q1 + 64 k1 + 128 q2 + 128 k2 + 1024 v
#define MROWS (BATCH * NSEQ)  // 4096
#define PCOLS 384             // proj2 keeps only q1/k1/q2/k2 columns
#define SCALE 0.17677669529663687f   // (R1*R2)^-0.5
#define SCALE_LOG2E 0.2550348612f    // SCALE * log2(e): scores in log2 domain

typedef __attribute__((ext_vector_type(8))) short bf16x8;
typedef __attribute__((ext_vector_type(4))) float f32x4;
typedef __attribute__((ext_vector_type(4))) unsigned int u32x4;

// ---------------- bf16 helpers (raw ushort representation) ----------------
__device__ __forceinline__ float bflo(unsigned u) { return __uint_as_float(u << 16); }
__device__ __forceinline__ float bfhi(unsigned u) { return __uint_as_float(u & 0xffff0000u); }
__device__ __forceinline__ unsigned short f2bfr(float f) {
  unsigned u = __float_as_uint(f);
  u += 0x7fffu + ((u >> 16) & 1u);
  return (unsigned short)(u >> 16);
}
__device__ __forceinline__ unsigned pack2(float a, float b) {
  return (unsigned)f2bfr(a) | ((unsigned)f2bfr(b) << 16);
}
// hardware packed f32x2 -> bf16x2 (RNE), single instruction (T12 recipe)
__device__ __forceinline__ unsigned cvtpk(float a, float b) {
  unsigned r;
  asm("v_cvt_pk_bf16_f32 %0, %1, %2" : "=v"(r) : "v"(a), "v"(b));
  return r;
}
// raw v_exp_f32 = 2^x (scores are kept in log2 domain)
__device__ __forceinline__ float exp2fast(float x) {
#if __has_builtin(__builtin_amdgcn_exp2f)
  return __builtin_amdgcn_exp2f(x);
#else
  float r;
  asm("v_exp_f32 %0, %1" : "=v"(r) : "v"(x));
  return r;
#endif
}

// ---------------- fused f32 -> bf16 conversion (all 7 inputs, 1 launch) ---
__global__ __launch_bounds__(256) void cvt_all_kernel(
    const float* __restrict__ x, const float* __restrict__ Wq1,
    const float* __restrict__ Wk1, const float* __restrict__ Wq2,
    const float* __restrict__ Wk2, const float* __restrict__ Wv,
    const float* __restrict__ Wo, unsigned short* __restrict__ xb,
    unsigned short* __restrict__ Wall, unsigned short* __restrict__ Wob) {
  const int total = 1671168;
  for (int i = blockIdx.x * blockDim.x + threadIdx.x; i < total;
       i += gridDim.x * blockDim.x) {
    const float* src;
    unsigned short* dst;
    int off;
    if (i < 1048576)      { src = x;   dst = xb;            off = i; }
    else if (i < 1064960) { src = Wq1; dst = Wall;          off = i - 1048576; }
    else if (i < 1081344) { src = Wk1; dst = Wall + 65536;  off = i - 1064960; }
    else if (i < 1114112) { src = Wq2; dst = Wall + 131072; off = i - 1081344; }
    else if (i < 1146880) { src = Wk2; dst = Wall + 262144; off = i - 1114112; }
    else if (i < 1409024) { src = Wv;  dst = Wall + 393216; off = i - 1146880; }
    else                  { src = Wo;  dst = Wob;           off = i - 1409024; }
    const float4 v = ((const float4*)src)[off];
    ushort4 o;
    o.x = f2bfr(v.x);
    o.y = f2bfr(v.y);
    o.z = f2bfr(v.z);
    o.w = f2bfr(v.w);
    ((ushort4*)dst)[off] = o;
  }
}

// ---------------- async global->LDS (16B per lane) ----------------
__device__ __forceinline__ void gld_lds16(const void* g, void* l) {
  __builtin_amdgcn_global_load_lds(
      (const __attribute__((address_space(1))) void*)g,
      (__attribute__((address_space(3))) void*)l, 16, 0, 0);
}

// ---------------- bf16 GEMM: C[M][N] = A[M][K] * Bw[N][K]^T ----------------
// 64x128 tile, BK=32, double-buffered LDS, one barrier per K-step (R14).
// 1D grid + XCD-chunked decode (R16/T1). R18 both-sides LDS XOR swizzle.
// OUTMODE 0 (proj): cols<384 -> proj2 rows; cols>=384 -> transposed vt.
// OUTMODE 1 (out): f32 + bias.
template <int OUTMODE>
__global__ __launch_bounds__(256) void gemm_bt64(
    const unsigned short* __restrict__ A, const unsigned short* __restrict__ Bw,
    unsigned short* __restrict__ Cb, unsigned short* __restrict__ vtout,
    float* __restrict__ Cf, const float* __restrict__ bias, int M, int N,
    int K) {
  __shared__ unsigned short As[2][64 * 32];   // 2 x 4 KB
  __shared__ unsigned short Bs[2][128 * 32];  // 2 x 8 KB
  const int tid = threadIdx.x;
  const int bid = blockIdx.x;
  const int xcd = bid & 7;
  const int ii = bid >> 3;
  const int nx = N >> 7;                 // blocks along N
  const int by = xcd * 8 + ii / nx;      // (M/64)/8 == 8 panels per XCD
  const int bx = ii - (ii / nx) * nx;
  const long brow = (long)by * 64;
  const long bcol = (long)bx * 128;
  const int w = tid >> 6, lane = tid & 63;
  const int lr = lane & 15, kg = lane >> 4;

  f32x4 acc[4][2];
#pragma unroll
  for (int m = 0; m < 4; ++m)
#pragma unroll
    for (int n = 0; n < 2; ++n) acc[m][n] = (f32x4){0.f, 0.f, 0.f, 0.f};

  const int off0 = tid * 16;
  const int row0 = off0 >> 6;
  // pre-swizzled global source chunk (involution with the read XOR)
  const int kel0 = (((tid & 3) ^ ((tid >> 3) & 3)) << 3);
  // swizzled read chunk offset (elements); lane-constant for all m/n rows
  const int kgx = ((kg ^ ((lr >> 1) & 3)) << 3);

  const int nk = K >> 5;
  // prologue: stage kt=0 into buffer 0
  {
    gld_lds16(A + (brow + row0) * K + kel0, (char*)As[0] + off0);
    gld_lds16(Bw + (bcol + row0) * K + kel0, (char*)Bs[0] + off0);
    gld_lds16(Bw + (bcol + 64 + row0) * K + kel0, (char*)Bs[0] + 4096 + off0);
  }
  __syncthreads();

  int buf = 0;
  for (int kt = 0; kt < nk; ++kt) {
    if (kt + 1 < nk) {  // stage next K-step (hides under this step's MFMA)
      const long kbase = (long)(kt + 1) * 32 + kel0;
      gld_lds16(A + (brow + row0) * K + kbase, (char*)As[buf ^ 1] + off0);
      gld_lds16(Bw + (bcol + row0) * K + kbase, (char*)Bs[buf ^ 1] + off0);
      gld_lds16(Bw + (bcol + 64 + row0) * K + kbase,
                (char*)Bs[buf ^ 1] + 4096 + off0);
    }

    bf16x8 af[4], bfg[2];
#pragma unroll
    for (int m = 0; m < 4; ++m)
      af[m] = *(const bf16x8*)(As[buf] + (m * 16 + lr) * 32 + kgx);
#pragma unroll
    for (int n = 0; n < 2; ++n)
      bfg[n] = *(const bf16x8*)(Bs[buf] + (w * 32 + n * 16 + lr) * 32 + kgx);
#pragma unroll
    for (int m = 0; m < 4; ++m)
#pragma unroll
      for (int n = 0; n < 2; ++n)
        acc[m][n] = __builtin_amdgcn_mfma_f32_16x16x32_bf16(af[m], bfg[n],
                                                            acc[m][n], 0, 0, 0);
    __syncthreads();  // drains next-step stage loads + protects buffers
    buf ^= 1;
  }

  // epilogue; C/D layout: col = lane&15, row = (lane>>4)*4 + i
  if (OUTMODE == 1) {
#pragma unroll
    for (int m = 0; m < 4; ++m) {
#pragma unroll
      for (int i = 0; i < 4; ++i) {
        const long r = brow + m * 16 + kg * 4 + i;
#pragma unroll
        for (int n = 0; n < 2; ++n) {
          const long c = bcol + w * 32 + n * 16 + lr;
          Cf[r * N + c] = acc[m][n][i] + bias[c];
        }
      }
    }
  } else if (bcol < PCOLS) {  // proj columns -> row-major proj2
#pragma unroll
    for (int m = 0; m < 4; ++m) {
#pragma unroll
      for (int i = 0; i < 4; ++i) {
        const long r = brow + m * 16 + kg * 4 + i;
#pragma unroll
        for (int n = 0; n < 2; ++n) {
          const long c = bcol + w * 32 + n * 16 + lr;
          Cb[r * PCOLS + c] = f2bfr(acc[m][n][i]);
        }
      }
    }
  } else {  // V columns -> transposed write into vt[bh][d][n]
    const int bb = (int)(brow >> 11);        // batch (constant per block)
    const int nn0 = (int)(brow & 2047);
#pragma unroll
    for (int n = 0; n < 2; ++n) {
      const int hd = (int)(bcol + w * 32 + n * 16 + lr) - 384;
      const int h = hd >> 6, d = hd & 63;
      unsigned short* base =
          vtout + ((size_t)((bb * 16 + h) * 64 + d)) * NSEQ + nn0;
#pragma unroll
      for (int m = 0; m < 4; ++m) {
        uint2 u;
        u.x = pack2(acc[m][n][0], acc[m][n][1]);
        u.y = pack2(acc[m][n][2], acc[m][n][3]);
        *(uint2*)(base + m * 16 + kg * 4) = u;
      }
    }
  }
}

// ---------------- kron feature build: qf/kf[bh][n][32] -------------------
// reads proj2 rows (stride PCOLS=384)
__global__ __launch_bounds__(256) void kron_kernel(
    const unsigned short* __restrict__ proj, unsigned short* __restrict__ qf,
    unsigned short* __restrict__ kf) {
  const int bh = blockIdx.x, b = bh >> 4, h = bh & 15;
  const int n = blockIdx.y * 256 + threadIdx.x;
  const unsigned short* row = proj + ((size_t)(b * NSEQ + n)) * PCOLS;
  float q1v[4], k1v[4], q2v[8], k2v[8];
  {
    const uint2 a = *(const uint2*)(row + h * 4);
    q1v[0] = bflo(a.x); q1v[1] = bfhi(a.x); q1v[2] = bflo(a.y); q1v[3] = bfhi(a.y);
    const uint2 c = *(const uint2*)(row + 64 + h * 4);
    k1v[0] = bflo(c.x); k1v[1] = bfhi(c.x); k1v[2] = bflo(c.y); k1v[3] = bfhi(c.y);
    const uint4 d = *(const uint4*)(row + 128 + h * 8);
    q2v[0] = bflo(d.x); q2v[1] = bfhi(d.x); q2v[2] = bflo(d.y); q2v[3] = bfhi(d.y);
    q2v[4] = bflo(d.z); q2v[5] = bfhi(d.z); q2v[6] = bflo(d.w); q2v[7] = bfhi(d.w);
    const uint4 e = *(const uint4*)(row + 256 + h * 8);
    k2v[0] = bflo(e.x); k2v[1] = bfhi(e.x); k2v[2] = bflo(e.y); k2v[3] = bfhi(e.y);
    k2v[4] = bflo(e.z); k2v[5] = bfhi(e.z); k2v[6] = bflo(e.w); k2v[7] = bfhi(e.w);
  }
  unsigned short* oq = qf + ((size_t)bh * NSEQ + n) * 32;
  unsigned short* ok = kf + ((size_t)bh * NSEQ + n) * 32;
#pragma unroll
  for (int i = 0; i < 4; ++i) {
    const float qs = q1v[i] * SCALE_LOG2E;
    uint4 uq, uk;
    uq.x = pack2(qs * q2v[0], qs * q2v[1]);
    uq.y = pack2(qs * q2v[2], qs * q2v[3]);
    uq.z = pack2(qs * q2v[4], qs * q2v[5]);
    uq.w = pack2(qs * q2v[6], qs * q2v[7]);
    uk.x = pack2(k1v[i] * k2v[0], k1v[i] * k2v[1]);
    uk.y = pack2(k1v[i] * k2v[2], k1v[i] * k2v[3]);
    uk.z = pack2(k1v[i] * k2v[4], k1v[i] * k2v[5]);
    uk.w = pack2(k1v[i] * k2v[6], k1v[i] * k2v[7]);
    *(uint4*)(oq + i * 8) = uq;
    *(uint4*)(ok + i * 8) = uk;
  }
}

// ---------------- flash attention: 8 waves x 16 q-rows (R19) --------------
// Same 128-q blocks/tables/math as R16-R18; each wave now owns ONE 16-row
// q-fragment -> per-wave VGPR state halves (oA[4]+lacA+qA ~ 24) so 8
// waves/SIMD can be resident (vs 5) — TLP covers the score->exp2->PV chain.
// Staging re-mapped for 512 threads, producing the IDENTICAL LDS image:
//   V: row=tid>>3, chunk-XOR (tid&7)^((tid>>3)&7), one gld/buffer (8KB)
//   K: tid<256: row=tid>>2, chunk-XOR (tid&3)^((tid>>5)&3)        (4KB)
// Read-side offsets (koffA, vx) unchanged.
__constant__ int QI_TAB[40] = {3,7,7,10,11,11,11,14,14,15,15,15,15,
                               6,6,9,9,10,10,12,12,13,13,13,13,14,14,
                               2,5,5,8,8,8,9,12,12, 4,4, 1, 0};
__constant__ int C_TAB[40]  = {0,0,1,2,0,1,2,1,3,0,1,2,3,
                               0,1,1,2,0,1,1,3,0,1,2,3,0,2,
                               0,0,1,0,1,2,0,0,2, 0,1, 0, 0};
__constant__ int NCQ[16]   = {1,1,1,1,2,2,2,2,3,3,3,3,4,4,4,4};
__constant__ int EBASE[16] = {0,0,0,0,0,1,2,3,4,6,8,10,12,15,18,21};

__global__ __launch_bounds__(512) void attn_flash(
    const unsigned short* __restrict__ qf, const unsigned short* __restrict__ kf,
    const unsigned short* __restrict__ vt, unsigned short* __restrict__ ao,
    unsigned short* __restrict__ po, unsigned short* __restrict__ po2,
    float* __restrict__ lst) {
  __shared__ __align__(16) char KsB[2 * 4096];  // [2 buf][64 keys][32 feat]
  __shared__ __align__(16) char VsB[2 * 8192];  // [2 buf][64 d][64 keys]

  const int bid = blockIdx.x;
  const int xcd = bid & 7;
  const int idx = bid >> 3;        // [0,160) per XCD
  const int j = idx >> 2;          // item [0,40), heavy-first
  const int g = idx & 3;           // head group
  const int bh = g * 8 + xcd;
  const int qi = QI_TAB[j];
  const int c = C_TAB[j];
  const int nc = NCQ[qi];
  const int T64 = 2 * qi + 2;
  const int tb = (c * T64) / nc;
  const int te = ((c + 1) * T64) / nc;

  const int tid = threadIdx.x;
  const int w = tid >> 6;          // wave 0..7 -> 16-row q fragment
  const int lane = tid & 63;
  const int lr = lane & 15, kg = lane >> 4;
  const int b = bh >> 4, h = bh & 15;
  const int qbase = qi * 128 + w * 16;
  const int q0 = qbase + lr;
  const int qmaxW = qbase + 15;

  const unsigned short* qfh = qf + (size_t)bh * NSEQ * 32;
  const unsigned short* kfh = kf + (size_t)bh * NSEQ * 32;
  const unsigned short* vth = vt + (size_t)bh * 64 * NSEQ;

  const bf16x8 qA = *(const bf16x8*)(qfh + q0 * 32 + kg * 8);
  const int krow = (lr >> 2) * 8 + (lr & 3);  // permuted key row for A-frag
  const f32x4 zero = (f32x4){0.f, 0.f, 0.f, 0.f};

  union { u32x4 u; bf16x8 hv; } onesu;
  onesu.u = (u32x4){0x3F803F80u, 0x3F803F80u, 0x3F803F80u, 0x3F803F80u};
  const bf16x8 vones = onesu.hv;  // bf16 1.0 x 8 (A-operand of the l-MFMA)

  const int koffA = krow * 64 + 16 * (kg ^ (lr >> 2));
  const int vx = lr & 7;

  // staging maps (512 threads; same LDS image as R18):
  const int krw = tid >> 2;                       // K row 0..63 (tid<256)
  const int ksoff = 8 * ((tid & 3) ^ ((tid >> 5) & 3));
  const int vdr = tid >> 3;                       // V row 0..63
  const int vsoff = 8 * ((tid & 7) ^ (vdr & 7));

  f32x4 oA[4], lacA;
#pragma unroll
  for (int dt = 0; dt < 4; ++dt) oA[dt] = zero;
  lacA = zero;

  // ---- prologue: stage super-tile tb into buffer 0
  {
    const int k0 = tb * 64;
    if (tid < 256)
      gld_lds16(kfh + (size_t)(k0 + krw) * 32 + ksoff, KsB + tid * 16);
    gld_lds16(vth + (size_t)vdr * NSEQ + k0 + vsoff, VsB + tid * 16);
  }
  __syncthreads();

  int buf = 0;
  for (int st = tb; st < te; ++st) {
    if (st + 1 < te) {  // stage next super-tile (latency hides under compute)
      const int kn = (st + 1) * 64;
      const int ob = buf ^ 1;
      if (tid < 256)
        gld_lds16(kfh + (size_t)(kn + krw) * 32 + ksoff,
                  KsB + ob * 4096 + tid * 16);
      gld_lds16(vth + (size_t)vdr * NSEQ + kn + vsoff,
                VsB + ob * 8192 + tid * 16);
    }
    const char* Kb = KsB + buf * 4096;
    const char* Vb = VsB + buf * 8192;
#pragma unroll
    for (int sub = 0; sub < 2; ++sub) {
      const int k032 = st * 64 + sub * 32;
      if (k032 <= qmaxW) {  // not fully masked for this wave
        __builtin_amdgcn_s_setprio(1);
        const bf16x8 ck0 = *(const bf16x8*)(Kb + sub * 2048 + koffA);
        const bf16x8 ck1 = *(const bf16x8*)(Kb + sub * 2048 + koffA + 256);

        f32x4 sA0 = __builtin_amdgcn_mfma_f32_16x16x32_bf16(ck0, qA, zero, 0, 0, 0);
        f32x4 sA1 = __builtin_amdgcn_mfma_f32_16x16x32_bf16(ck1, qA, zero, 0, 0, 0);

        if (k032 + 31 > qbase) {  // diagonal region: causal mask
          const int kb = k032 + kg * 8;
#pragma unroll
          for (int i = 0; i < 4; ++i) {
            if (kb + i > q0) sA0[i] = -1e30f;
            if (kb + 4 + i > q0) sA1[i] = -1e30f;
          }
        }

        // static-shift softmax: p = exp2(s) directly (m = 0)
        const float a0 = exp2fast(sA0[0]), a1 = exp2fast(sA0[1]);
        const float a2 = exp2fast(sA0[2]), a3 = exp2fast(sA0[3]);
        const float a4 = exp2fast(sA1[0]), a5 = exp2fast(sA1[1]);
        const float a6 = exp2fast(sA1[2]), a7 = exp2fast(sA1[3]);

        union { u32x4 u; bf16x8 hv; } pA;
        pA.u = (u32x4){cvtpk(a0, a1), cvtpk(a2, a3), cvtpk(a4, a5), cvtpk(a6, a7)};

        // softmax denominator on the matrix pipe: l[q] += sum_k p[k][q]
        lacA = __builtin_amdgcn_mfma_f32_16x16x32_bf16(vones, pA.hv, lacA, 0, 0, 0);

#pragma unroll
        for (int dt = 0; dt < 4; ++dt) {
          const bf16x8 vfr = *(const bf16x8*)(
              Vb + (dt * 16 + lr) * 128 + ((((sub * 4 + kg) ^ vx) << 4)));
          oA[dt] = __builtin_amdgcn_mfma_f32_16x16x32_bf16(vfr, pA.hv, oA[dt], 0, 0, 0);
        }
        __builtin_amdgcn_s_setprio(0);
      }
    }
    __syncthreads();  // drains next-tile stage loads + protects buffers
    buf ^= 1;
  }

  // denominator: every lane's lacA rows all equal sum_k p[k][q] (A=ones)
  const float ltA = lacA[0];

  if (nc == 1) {  // qi 0..3: direct normalized write
    const float invA = 1.f / ltA;
    unsigned short* pAo = ao + ((size_t)(b * NSEQ + q0)) * CDIM + h * 64 + kg * 4;
#pragma unroll
    for (int dt = 0; dt < 4; ++dt) {
      uint2 ua;
      ua.x = pack2(oA[dt][0] * invA, oA[dt][1] * invA);
      ua.y = pack2(oA[dt][2] * invA, oA[dt][3] * invA);
      *(uint2*)(pAo + dt * 16) = ua;
    }
  } else {  // unnormalized O: chunk 0 -> ao rows (in place), else -> po slot
    unsigned short* pAo;
    if (c == 0) {
      pAo = ao + ((size_t)(b * NSEQ + q0)) * CDIM + h * 64 + kg * 4;
    } else {
      const int slot = bh * 24 + EBASE[qi] + (c - 1);  // [0,768)
      unsigned short* sp = (slot < 704)
                               ? po + (size_t)slot * 8192
                               : po2 + (size_t)(slot - 704) * 8192;
      pAo = sp + (w * 16 + lr) * 64 + kg * 4;
    }
#pragma unroll
    for (int dt = 0; dt < 4; ++dt) {
      uint2 ua;
      ua.x = pack2(oA[dt][0], oA[dt][1]);
      ua.y = pack2(oA[dt][2], oA[dt][3]);
      *(uint2*)(pAo + dt * 16) = ua;
    }
    if (kg == 0) {
      float* lp = lst + (((size_t)(bh * 16 + qi) * 4 + c) << 7);
      lp[w * 16 + lr] = ltA;
    }
  }
}

// ---------------- merge: ao_row = (ao_row + sum(po chunks)) / sum(l) ------
__global__ __launch_bounds__(256) void merge_kernel(
    const unsigned short* __restrict__ po, const unsigned short* __restrict__ po2,
    const float* __restrict__ lst, unsigned short* __restrict__ ao) {
  const int idx = blockIdx.x * 256 + threadIdx.x;  // [0, 393216)
  const int dc = idx & 7;
  const int t = idx >> 3;
  const int r = t & 127;
  const int u = t >> 7;  // [0, 384) = bh*12 + (qi-4)
  const int qi = 4 + (u % 12);
  const int bh = u / 12;
  const int nc = NCQ[qi];
  const int b = bh >> 4, h = bh & 15;

  float L = 0.f;
  const float* lp = lst + (((size_t)(bh * 16 + qi)) << 9);
  for (int c2 = 0; c2 < nc; ++c2) L += lp[(c2 << 7) + r];

  unsigned short* dst =
      ao + ((size_t)(b * NSEQ + qi * 128 + r)) * CDIM + h * 64 + dc * 8;
  const uint4 u0 = *(const uint4*)dst;
  float a0 = bflo(u0.x), a1 = bfhi(u0.x), a2 = bflo(u0.y), a3 = bfhi(u0.y);
  float a4 = bflo(u0.z), a5 = bfhi(u0.z), a6 = bflo(u0.w), a7 = bfhi(u0.w);
  for (int c2 = 1; c2 < nc; ++c2) {
    const int slot = bh * 24 + EBASE[qi] + (c2 - 1);
    const unsigned short* sp = (slot < 704)
                                   ? po + (size_t)slot * 8192
                                   : po2 + (size_t)(slot - 704) * 8192;
    const uint4 up = *(const uint4*)(sp + r * 64 + dc * 8);
    a0 += bflo(up.x); a1 += bfhi(up.x); a2 += bflo(up.y); a3 += bfhi(up.y);
    a4 += bflo(up.z); a5 += bfhi(up.z); a6 += bflo(up.w); a7 += bfhi(up.w);
  }
  const float inv = 1.f / L;
  uint4 o;
  o.x = pack2(a0 * inv, a1 * inv);
  o.y = pack2(a2 * inv, a3 * inv);
  o.z = pack2(a4 * inv, a5 * inv);
  o.w = pack2(a6 * inv, a7 * inv);
  *(uint4*)dst = o;
}

// ---------------- launch ----------------
extern "C" void kernel_launch(void* const* d_in, const int* in_sizes, int n_in,
                              void* d_out, int out_size, void* d_ws,
                              size_t ws_size, hipStream_t stream) {
  (void)in_sizes; (void)n_in; (void)out_size; (void)ws_size;
  const float* x   = (const float*)d_in[0];
  const float* Wq1 = (const float*)d_in[1];
  const float* Wk1 = (const float*)d_in[2];
  const float* Wq2 = (const float*)d_in[3];
  const float* Wk2 = (const float*)d_in[4];
  const float* Wv  = (const float*)d_in[5];
  const float* Wo  = (const float*)d_in[6];
  const float* bo  = (const float*)d_in[7];
  float* out = (float*)d_out;

  char* ws = (char*)d_ws;
  unsigned short* xb   = (unsigned short*)(ws);              // 8 MB (reused as ao)
  unsigned short* Wall = (unsigned short*)(ws + 8388608);    // 2,883,584 B
  unsigned short* Wob  = (unsigned short*)(ws + 11272192);   // 2 MB
  unsigned short* proj = (unsigned short*)(ws + 13369344);   // proj2: 3 MB used
  unsigned short* qf   = (unsigned short*)(ws + 24903680);   // 4 MB
  unsigned short* kf   = (unsigned short*)(ws + 29097984);   // 4 MB
  unsigned short* vt   = (unsigned short*)(ws + 33292288);   // 8 MB
  unsigned short* ao   = xb;  // xb dead after proj GEMM
  // split-K partial slots (16KB each): 704 overlay proj region (dead after
  // kron), 64 overlay Wall (dead after proj GEMM); l-stats after po2.
  unsigned short* po   = proj;
  unsigned short* po2  = Wall;
  float*          lst  = (float*)(ws + 8388608 + 1048576);   // 1 MB

  cvt_all_kernel<<<dim3(2048), dim3(256), 0, stream>>>(
      x, Wq1, Wk1, Wq2, Wk2, Wv, Wo, xb, Wall, Wob);

  // proj GEMM: cols<384 -> proj2 rows; cols>=384 -> transposed V into vt
  gemm_bt64<0><<<dim3((NPROJ / 128) * (MROWS / 64)), dim3(256), 0, stream>>>(
      xb, Wall, proj, vt, (float*)nullptr, (const float*)nullptr, MROWS,
      NPROJ, CDIM);

  kron_kernel<<<dim3(BATCH * HHEADS, NSEQ / 256), dim3(256), 0, stream>>>(proj, qf, kf);

  attn_flash<<<dim3(1280), dim3(512), 0, stream>>>(qf, kf, vt, ao, po, po2, lst);
  merge_kernel<<<dim3(1536), dim3(256), 0, stream>>>(po, po2, lst, ao);

  gemm_bt64<1><<<dim3((CDIM / 128) * (MROWS / 64)), dim3(256), 0, stream>>>(
      ao, Wob, (unsigned short*)nullptr, (unsigned short*)nullptr, out, bo,
      MROWS, CDIM, CDIM);
}

// Round 20
// 92.720 us; speedup vs baseline: 1.1678x; 1.0072x over previous
//
#include <hip/hip_runtime.h>

// ---------------- problem constants ----------------
#define HHEADS 16
#define R1 4
#define R2 8
#define HD 64
#define CDIM 1024
#define NSEQ 2048
#define BATCH 2
#define NPROJ 1408            // 64 q1 + 64 k1 + 128 q2 + 128 k2 + 1024 v
#define MROWS (BATCH * NSEQ)  // 4096
#define PCOLS 384             // proj2 keeps only q1/k1/q2/k2 columns
#define SCALE 0.17677669529663687f   // (R1*R2)^-0.5
#define SCALE_LOG2E 0.2550348612f    // SCALE * log2(e): scores in log2 domain

typedef __attribute__((ext_vector_type(8))) short bf16x8;
typedef __attribute__((ext_vector_type(4))) float f32x4;
typedef __attribute__((ext_vector_type(4))) unsigned int u32x4;

// ---------------- bf16 helpers (raw ushort representation) ----------------
__device__ __forceinline__ float bflo(unsigned u) { return __uint_as_float(u << 16); }
__device__ __forceinline__ float bfhi(unsigned u) { return __uint_as_float(u & 0xffff0000u); }
__device__ __forceinline__ unsigned short f2bfr(float f) {
  unsigned u = __float_as_uint(f);
  u += 0x7fffu + ((u >> 16) & 1u);
  return (unsigned short)(u >> 16);
}
__device__ __forceinline__ unsigned pack2(float a, float b) {
  return (unsigned)f2bfr(a) | ((unsigned)f2bfr(b) << 16);
}
// hardware packed f32x2 -> bf16x2 (RNE), single instruction (T12 recipe)
__device__ __forceinline__ unsigned cvtpk(float a, float b) {
  unsigned r;
  asm("v_cvt_pk_bf16_f32 %0, %1, %2" : "=v"(r) : "v"(a), "v"(b));
  return r;
}
// raw v_exp_f32 = 2^x (scores are kept in log2 domain)
__device__ __forceinline__ float exp2fast(float x) {
#if __has_builtin(__builtin_amdgcn_exp2f)
  return __builtin_amdgcn_exp2f(x);
#else
  float r;
  asm("v_exp_f32 %0, %1" : "=v"(r) : "v"(x));
  return r;
#endif
}

// ---------------- fused f32 -> bf16 conversion (all 7 inputs, 1 launch) ---
__global__ __launch_bounds__(256) void cvt_all_kernel(
    const float* __restrict__ x, const float* __restrict__ Wq1,
    const float* __restrict__ Wk1, const float* __restrict__ Wq2,
    const float* __restrict__ Wk2, const float* __restrict__ Wv,
    const float* __restrict__ Wo, unsigned short* __restrict__ xb,
    unsigned short* __restrict__ Wall, unsigned short* __restrict__ Wob) {
  const int total = 1671168;
  for (int i = blockIdx.x * blockDim.x + threadIdx.x; i < total;
       i += gridDim.x * blockDim.x) {
    const float* src;
    unsigned short* dst;
    int off;
    if (i < 1048576)      { src = x;   dst = xb;            off = i; }
    else if (i < 1064960) { src = Wq1; dst = Wall;          off = i - 1048576; }
    else if (i < 1081344) { src = Wk1; dst = Wall + 65536;  off = i - 1064960; }
    else if (i < 1114112) { src = Wq2; dst = Wall + 131072; off = i - 1081344; }
    else if (i < 1146880) { src = Wk2; dst = Wall + 262144; off = i - 1114112; }
    else if (i < 1409024) { src = Wv;  dst = Wall + 393216; off = i - 1146880; }
    else                  { src = Wo;  dst = Wob;           off = i - 1409024; }
    const float4 v = ((const float4*)src)[off];
    ushort4 o;
    o.x = f2bfr(v.x);
    o.y = f2bfr(v.y);
    o.z = f2bfr(v.z);
    o.w = f2bfr(v.w);
    ((ushort4*)dst)[off] = o;
  }
}

// ---------------- async global->LDS (16B per lane) ----------------
__device__ __forceinline__ void gld_lds16(const void* g, void* l) {
  __builtin_amdgcn_global_load_lds(
      (const __attribute__((address_space(1))) void*)g,
      (__attribute__((address_space(3))) void*)l, 16, 0, 0);
}

// ---------------- bf16 GEMM: C[M][N] = A[M][K] * Bw[N][K]^T ----------------
// 64x128 tile, BK=32, double-buffered LDS, one barrier per K-step (R14).
// 1D grid + XCD-chunked decode (R16/T1). R18 both-sides LDS XOR swizzle.
// OUTMODE 0 (proj): cols<384 -> proj2 rows; cols>=384 -> transposed vt.
// OUTMODE 1 (out): f32 + bias.
template <int OUTMODE>
__global__ __launch_bounds__(256) void gemm_bt64(
    const unsigned short* __restrict__ A, const unsigned short* __restrict__ Bw,
    unsigned short* __restrict__ Cb, unsigned short* __restrict__ vtout,
    float* __restrict__ Cf, const float* __restrict__ bias, int M, int N,
    int K) {
  __shared__ unsigned short As[2][64 * 32];   // 2 x 4 KB
  __shared__ unsigned short Bs[2][128 * 32];  // 2 x 8 KB
  const int tid = threadIdx.x;
  const int bid = blockIdx.x;
  const int xcd = bid & 7;
  const int ii = bid >> 3;
  const int nx = N >> 7;                 // blocks along N
  const int by = xcd * 8 + ii / nx;      // (M/64)/8 == 8 panels per XCD
  const int bx = ii - (ii / nx) * nx;
  const long brow = (long)by * 64;
  const long bcol = (long)bx * 128;
  const int w = tid >> 6, lane = tid & 63;
  const int lr = lane & 15, kg = lane >> 4;

  f32x4 acc[4][2];
#pragma unroll
  for (int m = 0; m < 4; ++m)
#pragma unroll
    for (int n = 0; n < 2; ++n) acc[m][n] = (f32x4){0.f, 0.f, 0.f, 0.f};

  const int off0 = tid * 16;
  const int row0 = off0 >> 6;
  // pre-swizzled global source chunk (involution with the read XOR)
  const int kel0 = (((tid & 3) ^ ((tid >> 3) & 3)) << 3);
  // swizzled read chunk offset (elements); lane-constant for all m/n rows
  const int kgx = ((kg ^ ((lr >> 1) & 3)) << 3);

  const int nk = K >> 5;
  // prologue: stage kt=0 into buffer 0
  {
    gld_lds16(A + (brow + row0) * K + kel0, (char*)As[0] + off0);
    gld_lds16(Bw + (bcol + row0) * K + kel0, (char*)Bs[0] + off0);
    gld_lds16(Bw + (bcol + 64 + row0) * K + kel0, (char*)Bs[0] + 4096 + off0);
  }
  __syncthreads();

  int buf = 0;
  for (int kt = 0; kt < nk; ++kt) {
    if (kt + 1 < nk) {  // stage next K-step (hides under this step's MFMA)
      const long kbase = (long)(kt + 1) * 32 + kel0;
      gld_lds16(A + (brow + row0) * K + kbase, (char*)As[buf ^ 1] + off0);
      gld_lds16(Bw + (bcol + row0) * K + kbase, (char*)Bs[buf ^ 1] + off0);
      gld_lds16(Bw + (bcol + 64 + row0) * K + kbase,
                (char*)Bs[buf ^ 1] + 4096 + off0);
    }

    bf16x8 af[4], bfg[2];
#pragma unroll
    for (int m = 0; m < 4; ++m)
      af[m] = *(const bf16x8*)(As[buf] + (m * 16 + lr) * 32 + kgx);
#pragma unroll
    for (int n = 0; n < 2; ++n)
      bfg[n] = *(const bf16x8*)(Bs[buf] + (w * 32 + n * 16 + lr) * 32 + kgx);
#pragma unroll
    for (int m = 0; m < 4; ++m)
#pragma unroll
      for (int n = 0; n < 2; ++n)
        acc[m][n] = __builtin_amdgcn_mfma_f32_16x16x32_bf16(af[m], bfg[n],
                                                            acc[m][n], 0, 0, 0);
    __syncthreads();  // drains next-step stage loads + protects buffers
    buf ^= 1;
  }

  // epilogue; C/D layout: col = lane&15, row = (lane>>4)*4 + i
  if (OUTMODE == 1) {
#pragma unroll
    for (int m = 0; m < 4; ++m) {
#pragma unroll
      for (int i = 0; i < 4; ++i) {
        const long r = brow + m * 16 + kg * 4 + i;
#pragma unroll
        for (int n = 0; n < 2; ++n) {
          const long c = bcol + w * 32 + n * 16 + lr;
          Cf[r * N + c] = acc[m][n][i] + bias[c];
        }
      }
    }
  } else if (bcol < PCOLS) {  // proj columns -> row-major proj2
#pragma unroll
    for (int m = 0; m < 4; ++m) {
#pragma unroll
      for (int i = 0; i < 4; ++i) {
        const long r = brow + m * 16 + kg * 4 + i;
#pragma unroll
        for (int n = 0; n < 2; ++n) {
          const long c = bcol + w * 32 + n * 16 + lr;
          Cb[r * PCOLS + c] = f2bfr(acc[m][n][i]);
        }
      }
    }
  } else {  // V columns -> transposed write into vt[bh][d][n]
    const int bb = (int)(brow >> 11);        // batch (constant per block)
    const int nn0 = (int)(brow & 2047);
#pragma unroll
    for (int n = 0; n < 2; ++n) {
      const int hd = (int)(bcol + w * 32 + n * 16 + lr) - 384;
      const int h = hd >> 6, d = hd & 63;
      unsigned short* base =
          vtout + ((size_t)((bb * 16 + h) * 64 + d)) * NSEQ + nn0;
#pragma unroll
      for (int m = 0; m < 4; ++m) {
        uint2 u;
        u.x = pack2(acc[m][n][0], acc[m][n][1]);
        u.y = pack2(acc[m][n][2], acc[m][n][3]);
        *(uint2*)(base + m * 16 + kg * 4) = u;
      }
    }
  }
}

// ---------------- kron feature build: qf/kf[bh][n][32] -------------------
// reads proj2 rows (stride PCOLS=384)
__global__ __launch_bounds__(256) void kron_kernel(
    const unsigned short* __restrict__ proj, unsigned short* __restrict__ qf,
    unsigned short* __restrict__ kf) {
  const int bh = blockIdx.x, b = bh >> 4, h = bh & 15;
  const int n = blockIdx.y * 256 + threadIdx.x;
  const unsigned short* row = proj + ((size_t)(b * NSEQ + n)) * PCOLS;
  float q1v[4], k1v[4], q2v[8], k2v[8];
  {
    const uint2 a = *(const uint2*)(row + h * 4);
    q1v[0] = bflo(a.x); q1v[1] = bfhi(a.x); q1v[2] = bflo(a.y); q1v[3] = bfhi(a.y);
    const uint2 c = *(const uint2*)(row + 64 + h * 4);
    k1v[0] = bflo(c.x); k1v[1] = bfhi(c.x); k1v[2] = bflo(c.y); k1v[3] = bfhi(c.y);
    const uint4 d = *(const uint4*)(row + 128 + h * 8);
    q2v[0] = bflo(d.x); q2v[1] = bfhi(d.x); q2v[2] = bflo(d.y); q2v[3] = bfhi(d.y);
    q2v[4] = bflo(d.z); q2v[5] = bfhi(d.z); q2v[6] = bflo(d.w); q2v[7] = bfhi(d.w);
    const uint4 e = *(const uint4*)(row + 256 + h * 8);
    k2v[0] = bflo(e.x); k2v[1] = bfhi(e.x); k2v[2] = bflo(e.y); k2v[3] = bfhi(e.y);
    k2v[4] = bflo(e.z); k2v[5] = bfhi(e.z); k2v[6] = bflo(e.w); k2v[7] = bfhi(e.w);
  }
  unsigned short* oq = qf + ((size_t)bh * NSEQ + n) * 32;
  unsigned short* ok = kf + ((size_t)bh * NSEQ + n) * 32;
#pragma unroll
  for (int i = 0; i < 4; ++i) {
    const float qs = q1v[i] * SCALE_LOG2E;
    uint4 uq, uk;
    uq.x = pack2(qs * q2v[0], qs * q2v[1]);
    uq.y = pack2(qs * q2v[2], qs * q2v[3]);
    uq.z = pack2(qs * q2v[4], qs * q2v[5]);
    uq.w = pack2(qs * q2v[6], qs * q2v[7]);
    uk.x = pack2(k1v[i] * k2v[0], k1v[i] * k2v[1]);
    uk.y = pack2(k1v[i] * k2v[2], k1v[i] * k2v[3]);
    uk.z = pack2(k1v[i] * k2v[4], k1v[i] * k2v[5]);
    uk.w = pack2(k1v[i] * k2v[6], k1v[i] * k2v[7]);
    *(uint4*)(oq + i * 8) = uq;
    *(uint4*)(ok + i * 8) = uk;
  }
}

// ---------------- flash attention: KVBLK=128, 8 waves x 16 q-rows (R20) ---
// R19 structure with 128-key super-tiles: 4 compute-subs per barrier (half
// the barrier drains, 2x compute cover per staging wave). LDS 48 KB dbuf
// (K 8KB + V 16KB per buffer) -> 3 blocks/CU x 8 waves = 24 waves/CU.
// Chunk tables over T128 = qi+1 tiles (same 40 items/head, same key ranges).
// K swizzle identical (sub-offset is a multiple of 32 rows -> (row>>3)&3
// unchanged per lane). V rows widen to 256B -> 16-chunk swizzle:
// store chunk^(row&15), read (sub*4+kg)^lr (2 lanes/bank-pair = free).
__constant__ int QI_TAB[40] = {3,7,7,10,11,11,11,14,14,15,15,15,15,
                               6,6,9,9,10,10,12,12,13,13,13,13,14,14,
                               2,5,5,8,8,8,9,12,12, 4,4, 1, 0};
__constant__ int C_TAB[40]  = {0,0,1,2,0,1,2,1,3,0,1,2,3,
                               0,1,1,2,0,1,1,3,0,1,2,3,0,2,
                               0,0,1,0,1,2,0,0,2, 0,1, 0, 0};
__constant__ int NCQ[16]   = {1,1,1,1,2,2,2,2,3,3,3,3,4,4,4,4};
__constant__ int EBASE[16] = {0,0,0,0,0,1,2,3,4,6,8,10,12,15,18,21};

__global__ __launch_bounds__(512) void attn_flash(
    const unsigned short* __restrict__ qf, const unsigned short* __restrict__ kf,
    const unsigned short* __restrict__ vt, unsigned short* __restrict__ ao,
    unsigned short* __restrict__ po, unsigned short* __restrict__ po2,
    float* __restrict__ lst) {
  __shared__ __align__(16) char KsB[2 * 8192];   // [2 buf][128 keys][32 feat]
  __shared__ __align__(16) char VsB[2 * 16384];  // [2 buf][64 d][128 keys]

  const int bid = blockIdx.x;
  const int xcd = bid & 7;
  const int idx = bid >> 3;        // [0,160) per XCD
  const int j = idx >> 2;          // item [0,40), heavy-first
  const int g = idx & 3;           // head group
  const int bh = g * 8 + xcd;
  const int qi = QI_TAB[j];
  const int c = C_TAB[j];
  const int nc = NCQ[qi];
  const int T128 = qi + 1;         // 128-key super-tiles for this q-block
  const int tb = (c * T128) / nc;
  const int te = ((c + 1) * T128) / nc;

  const int tid = threadIdx.x;
  const int w = tid >> 6;          // wave 0..7 -> 16-row q fragment
  const int lane = tid & 63;
  const int lr = lane & 15, kg = lane >> 4;
  const int b = bh >> 4, h = bh & 15;
  const int qbase = qi * 128 + w * 16;
  const int q0 = qbase + lr;
  const int qmaxW = qbase + 15;

  const unsigned short* qfh = qf + (size_t)bh * NSEQ * 32;
  const unsigned short* kfh = kf + (size_t)bh * NSEQ * 32;
  const unsigned short* vth = vt + (size_t)bh * 64 * NSEQ;

  const bf16x8 qA = *(const bf16x8*)(qfh + q0 * 32 + kg * 8);
  const int krow = (lr >> 2) * 8 + (lr & 3);  // permuted key row for A-frag
  const f32x4 zero = (f32x4){0.f, 0.f, 0.f, 0.f};

  union { u32x4 u; bf16x8 hv; } onesu;
  onesu.u = (u32x4){0x3F803F80u, 0x3F803F80u, 0x3F803F80u, 0x3F803F80u};
  const bf16x8 vones = onesu.hv;  // bf16 1.0 x 8 (A-operand of the l-MFMA)

  const int koffA = krow * 64 + 16 * (kg ^ (lr >> 2));

  // staging maps (512 threads):
  const int krw = tid >> 2;                       // K row 0..127
  const int ksoff = 8 * ((tid & 3) ^ ((tid >> 5) & 3));
  const int vr0 = tid >> 4;                       // V rows 0..31 (issue 0)
  const int vs0 = 8 * ((tid & 15) ^ (vr0 & 15));
  const int vr1 = 32 + (tid >> 4);                // V rows 32..63 (issue 1)
  const int vs1 = 8 * ((tid & 15) ^ (vr1 & 15));

  f32x4 oA[4], lacA;
#pragma unroll
  for (int dt = 0; dt < 4; ++dt) oA[dt] = zero;
  lacA = zero;

  // ---- prologue: stage super-tile tb into buffer 0
  {
    const int k0 = tb * 128;
    gld_lds16(kfh + (size_t)(k0 + krw) * 32 + ksoff, KsB + tid * 16);
    gld_lds16(vth + (size_t)vr0 * NSEQ + k0 + vs0, VsB + tid * 16);
    gld_lds16(vth + (size_t)vr1 * NSEQ + k0 + vs1, VsB + 8192 + tid * 16);
  }
  __syncthreads();

  int buf = 0;
  for (int st = tb; st < te; ++st) {
    if (st + 1 < te) {  // stage next super-tile (latency hides under compute)
      const int kn = (st + 1) * 128;
      const int ob = buf ^ 1;
      gld_lds16(kfh + (size_t)(kn + krw) * 32 + ksoff,
                KsB + ob * 8192 + tid * 16);
      gld_lds16(vth + (size_t)vr0 * NSEQ + kn + vs0,
                VsB + ob * 16384 + tid * 16);
      gld_lds16(vth + (size_t)vr1 * NSEQ + kn + vs1,
                VsB + ob * 16384 + 8192 + tid * 16);
    }
    const char* Kb = KsB + buf * 8192;
    const char* Vb = VsB + buf * 16384;
#pragma unroll
    for (int sub = 0; sub < 4; ++sub) {
      const int k032 = st * 128 + sub * 32;
      if (k032 <= qmaxW) {  // not fully masked for this wave
        __builtin_amdgcn_s_setprio(1);
        const bf16x8 ck0 = *(const bf16x8*)(Kb + sub * 2048 + koffA);
        const bf16x8 ck1 = *(const bf16x8*)(Kb + sub * 2048 + koffA + 256);

        f32x4 sA0 = __builtin_amdgcn_mfma_f32_16x16x32_bf16(ck0, qA, zero, 0, 0, 0);
        f32x4 sA1 = __builtin_amdgcn_mfma_f32_16x16x32_bf16(ck1, qA, zero, 0, 0, 0);

        if (k032 + 31 > qbase) {  // diagonal region: causal mask
          const int kb = k032 + kg * 8;
#pragma unroll
          for (int i = 0; i < 4; ++i) {
            if (kb + i > q0) sA0[i] = -1e30f;
            if (kb + 4 + i > q0) sA1[i] = -1e30f;
          }
        }

        // static-shift softmax: p = exp2(s) directly (m = 0)
        const float a0 = exp2fast(sA0[0]), a1 = exp2fast(sA0[1]);
        const float a2 = exp2fast(sA0[2]), a3 = exp2fast(sA0[3]);
        const float a4 = exp2fast(sA1[0]), a5 = exp2fast(sA1[1]);
        const float a6 = exp2fast(sA1[2]), a7 = exp2fast(sA1[3]);

        union { u32x4 u; bf16x8 hv; } pA;
        pA.u = (u32x4){cvtpk(a0, a1), cvtpk(a2, a3), cvtpk(a4, a5), cvtpk(a6, a7)};

        // softmax denominator on the matrix pipe: l[q] += sum_k p[k][q]
        lacA = __builtin_amdgcn_mfma_f32_16x16x32_bf16(vones, pA.hv, lacA, 0, 0, 0);

#pragma unroll
        for (int dt = 0; dt < 4; ++dt) {
          const bf16x8 vfr = *(const bf16x8*)(
              Vb + (dt * 16 + lr) * 256 + ((((sub * 4 + kg) ^ lr) << 4)));
          oA[dt] = __builtin_amdgcn_mfma_f32_16x16x32_bf16(vfr, pA.hv, oA[dt], 0, 0, 0);
        }
        __builtin_amdgcn_s_setprio(0);
      }
    }
    __syncthreads();  // drains next-tile stage loads + protects buffers
    buf ^= 1;
  }

  // denominator: every lane's lacA rows all equal sum_k p[k][q] (A=ones)
  const float ltA = lacA[0];

  if (nc == 1) {  // qi 0..3: direct normalized write
    const float invA = 1.f / ltA;
    unsigned short* pAo = ao + ((size_t)(b * NSEQ + q0)) * CDIM + h * 64 + kg * 4;
#pragma unroll
    for (int dt = 0; dt < 4; ++dt) {
      uint2 ua;
      ua.x = pack2(oA[dt][0] * invA, oA[dt][1] * invA);
      ua.y = pack2(oA[dt][2] * invA, oA[dt][3] * invA);
      *(uint2*)(pAo + dt * 16) = ua;
    }
  } else {  // unnormalized O: chunk 0 -> ao rows (in place), else -> po slot
    unsigned short* pAo;
    if (c == 0) {
      pAo = ao + ((size_t)(b * NSEQ + q0)) * CDIM + h * 64 + kg * 4;
    } else {
      const int slot = bh * 24 + EBASE[qi] + (c - 1);  // [0,768)
      unsigned short* sp = (slot < 704)
                               ? po + (size_t)slot * 8192
                               : po2 + (size_t)(slot - 704) * 8192;
      pAo = sp + (w * 16 + lr) * 64 + kg * 4;
    }
#pragma unroll
    for (int dt = 0; dt < 4; ++dt) {
      uint2 ua;
      ua.x = pack2(oA[dt][0], oA[dt][1]);
      ua.y = pack2(oA[dt][2], oA[dt][3]);
      *(uint2*)(pAo + dt * 16) = ua;
    }
    if (kg == 0) {
      float* lp = lst + (((size_t)(bh * 16 + qi) * 4 + c) << 7);
      lp[w * 16 + lr] = ltA;
    }
  }
}

// ---------------- merge: ao_row = (ao_row + sum(po chunks)) / sum(l) ------
__global__ __launch_bounds__(256) void merge_kernel(
    const unsigned short* __restrict__ po, const unsigned short* __restrict__ po2,
    const float* __restrict__ lst, unsigned short* __restrict__ ao) {
  const int idx = blockIdx.x * 256 + threadIdx.x;  // [0, 393216)
  const int dc = idx & 7;
  const int t = idx >> 3;
  const int r = t & 127;
  const int u = t >> 7;  // [0, 384) = bh*12 + (qi-4)
  const int qi = 4 + (u % 12);
  const int bh = u / 12;
  const int nc = NCQ[qi];
  const int b = bh >> 4, h = bh & 15;

  float L = 0.f;
  const float* lp = lst + (((size_t)(bh * 16 + qi)) << 9);
  for (int c2 = 0; c2 < nc; ++c2) L += lp[(c2 << 7) + r];

  unsigned short* dst =
      ao + ((size_t)(b * NSEQ + qi * 128 + r)) * CDIM + h * 64 + dc * 8;
  const uint4 u0 = *(const uint4*)dst;
  float a0 = bflo(u0.x), a1 = bfhi(u0.x), a2 = bflo(u0.y), a3 = bfhi(u0.y);
  float a4 = bflo(u0.z), a5 = bfhi(u0.z), a6 = bflo(u0.w), a7 = bfhi(u0.w);
  for (int c2 = 1; c2 < nc; ++c2) {
    const int slot = bh * 24 + EBASE[qi] + (c2 - 1);
    const unsigned short* sp = (slot < 704)
                                   ? po + (size_t)slot * 8192
                                   : po2 + (size_t)(slot - 704) * 8192;
    const uint4 up = *(const uint4*)(sp + r * 64 + dc * 8);
    a0 += bflo(up.x); a1 += bfhi(up.x); a2 += bflo(up.y); a3 += bfhi(up.y);
    a4 += bflo(up.z); a5 += bfhi(up.z); a6 += bflo(up.w); a7 += bfhi(up.w);
  }
  const float inv = 1.f / L;
  uint4 o;
  o.x = pack2(a0 * inv, a1 * inv);
  o.y = pack2(a2 * inv, a3 * inv);
  o.z = pack2(a4 * inv, a5 * inv);
  o.w = pack2(a6 * inv, a7 * inv);
  *(uint4*)dst = o;
}

// ---------------- launch ----------------
extern "C" void kernel_launch(void* const* d_in, const int* in_sizes, int n_in,
                              void* d_out, int out_size, void* d_ws,
                              size_t ws_size, hipStream_t stream) {
  (void)in_sizes; (void)n_in; (void)out_size; (void)ws_size;
  const float* x   = (const float*)d_in[0];
  const float* Wq1 = (const float*)d_in[1];
  const float* Wk1 = (const float*)d_in[2];
  const float* Wq2 = (const float*)d_in[3];
  const float* Wk2 = (const float*)d_in[4];
  const float* Wv  = (const float*)d_in[5];
  const float* Wo  = (const float*)d_in[6];
  const float* bo  = (const float*)d_in[7];
  float* out = (float*)d_out;

  char* ws = (char*)d_ws;
  unsigned short* xb   = (unsigned short*)(ws);              // 8 MB (reused as ao)
  unsigned short* Wall = (unsigned short*)(ws + 8388608);    // 2,883,584 B
  unsigned short* Wob  = (unsigned short*)(ws + 11272192);   // 2 MB
  unsigned short* proj = (unsigned short*)(ws + 13369344);   // proj2: 3 MB used
  unsigned short* qf   = (unsigned short*)(ws + 24903680);   // 4 MB
  unsigned short* kf   = (unsigned short*)(ws + 29097984);   // 4 MB
  unsigned short* vt   = (unsigned short*)(ws + 33292288);   // 8 MB
  unsigned short* ao   = xb;  // xb dead after proj GEMM
  // split-K partial slots (16KB each): 704 overlay proj region (dead after
  // kron), 64 overlay Wall (dead after proj GEMM); l-stats after po2.
  unsigned short* po   = proj;
  unsigned short* po2  = Wall;
  float*          lst  = (float*)(ws + 8388608 + 1048576);   // 1 MB

  cvt_all_kernel<<<dim3(2048), dim3(256), 0, stream>>>(
      x, Wq1, Wk1, Wq2, Wk2, Wv, Wo, xb, Wall, Wob);

  // proj GEMM: cols<384 -> proj2 rows; cols>=384 -> transposed V into vt
  gemm_bt64<0><<<dim3((NPROJ / 128) * (MROWS / 64)), dim3(256), 0, stream>>>(
      xb, Wall, proj, vt, (float*)nullptr, (const float*)nullptr, MROWS,
      NPROJ, CDIM);

  kron_kernel<<<dim3(BATCH * HHEADS, NSEQ / 256), dim3(256), 0, stream>>>(proj, qf, kf);

  attn_flash<<<dim3(1280), dim3(512), 0, stream>>>(qf, kf, vt, ao, po, po2, lst);
  merge_kernel<<<dim3(1536), dim3(256), 0, stream>>>(po, po2, lst, ao);

  gemm_bt64<1><<<dim3((CDIM / 128) * (MROWS / 64)), dim3(256), 0, stream>>>(
      ao, Wob, (unsigned short*)nullptr, (unsigned short*)nullptr, out, bo,
      MROWS, CDIM, CDIM);
}